// Round 8
// baseline (275.163 us; speedup 1.0000x reference)
//
#include <hip/hip_runtime.h>
#include <math.h>

#define NV 6
#define FHH 32
#define FWW 96
#define PIMG (FHH*FWW)   // 3072
#define HH 64
#define WWD 64
#define PBEV (HH*WWD)    // 4096
#define HEADS 4
#define DHD 32
#define KROWS 288
#define BN_S 0.9999950000374996f
#define LN_EPS 1e-5f
#define ATT_SCALE 0.17677669529663687f  // 32^-0.5

typedef __attribute__((ext_vector_type(8))) short short8;
typedef __attribute__((ext_vector_type(4))) float f32x4;
typedef __attribute__((ext_vector_type(8))) unsigned short u16x8;

__device__ __forceinline__ float gelu_f(float x) {
    return 0.5f * x * (1.0f + erff(x * 0.70710678118654752f));
}

__device__ __forceinline__ unsigned short f2bf(float f) {
    union { float f; unsigned int u; } c; c.f = f;
    unsigned int r = (c.u + 0x7fffu + ((c.u >> 16) & 1u)) >> 16;
    return (unsigned short)r;
}

__device__ __forceinline__ float blockSum128(float v, float* red, int tid) {
    #pragma unroll
    for (int o = 32; o > 0; o >>= 1) v += __shfl_down(v, o, 64);
    __syncthreads();
    if ((tid & 63) == 0) red[tid >> 6] = v;
    __syncthreads();
    return red[0] + red[1];
}

// ---------- feature transpose + BN*relu : [n][128][3072] -> [n*3072][128] ----------
__global__ void k_trans(const float* __restrict__ feature, float* __restrict__ f_cl) {
    __shared__ float tile[32][33];
    int n = blockIdx.z, c0 = blockIdx.y * 32, p0 = blockIdx.x * 32;
    int tp = threadIdx.x & 31, tg = threadIdx.x >> 5;
    #pragma unroll
    for (int i = 0; i < 4; ++i) {
        int c = tg + 8 * i;
        tile[c][tp] = feature[((size_t)(n * 128 + c0 + c)) * PIMG + p0 + tp];
    }
    __syncthreads();
    int cw = threadIdx.x & 31, pg = threadIdx.x >> 5;
    #pragma unroll
    for (int i = 0; i < 4; ++i) {
        int p = pg + 8 * i;
        float v = fmaxf(tile[cw][p] * BN_S, 0.0f);
        f_cl[((size_t)(n * PIMG + p0 + p)) * 128 + c0 + cw] = v;
    }
}

// ---------- geometric image embedding -> kinit [n*3072][128] ----------
__global__ void k_embed(const float* __restrict__ I_inv, const float* __restrict__ E_inv,
                        const float* __restrict__ ie_w, const float* __restrict__ ce_w,
                        float* __restrict__ kinit) {
    const int TILE = 16;
    int n = blockIdx.y, p0 = blockIdx.x * TILE, t = threadIdx.x;
    __shared__ float red[2];
    const float* E  = E_inv + n * 16;
    const float* Ii = I_inv + n * 9;
    float cemb = E[3]  * ce_w[t*4+0] + E[7]  * ce_w[t*4+1]
               + E[11] * ce_w[t*4+2] + E[15] * ce_w[t*4+3];
    for (int pos = 0; pos < TILE; ++pos) {
        int p = p0 + pos;
        int h = p / FWW, w = p % FWW;
        float gx = (float)w * (768.0f / 95.0f);
        float gy = (float)h * (256.0f / 31.0f);
        float c0 = Ii[0]*gx + Ii[1]*gy + Ii[2];
        float c1 = Ii[3]*gx + Ii[4]*gy + Ii[5];
        float c2 = Ii[6]*gx + Ii[7]*gy + Ii[8];
        float d0 = E[0]*c0  + E[1]*c1  + E[2]*c2  + E[3];
        float d1 = E[4]*c0  + E[5]*c1  + E[6]*c2  + E[7];
        float d2 = E[8]*c0  + E[9]*c1  + E[10]*c2 + E[11];
        float d3 = E[12]*c0 + E[13]*c1 + E[14]*c2 + E[15];
        float emb = d0*ie_w[t*4+0] + d1*ie_w[t*4+1]
                  + d2*ie_w[t*4+2] + d3*ie_w[t*4+3] - cemb;
        float ss = blockSum128(emb * emb, red, t);
        kinit[((size_t)(n * PIMG + p)) * 128 + t] = emb / (sqrtf(ss) + 1e-7f);
    }
}

// ---------- query [n*4096][128] ----------
__global__ void k_query(const float* __restrict__ x, const float* __restrict__ bev,
                        const float* __restrict__ be_w, const float* __restrict__ be_b,
                        const float* __restrict__ E_inv, const float* __restrict__ ce_w,
                        float* __restrict__ query) {
    const int TILE = 16;
    int n = blockIdx.y, p0 = blockIdx.x * TILE, t = threadIdx.x;
    __shared__ float red[2];
    const float* E = E_inv + n * 16;
    float cemb = E[3]  * ce_w[t*4+0] + E[7]  * ce_w[t*4+1]
               + E[11] * ce_w[t*4+2] + E[15] * ce_w[t*4+3];
    float bw0 = be_w[t*2+0], bw1 = be_w[t*2+1], bb = be_b[t];
    for (int pos = 0; pos < TILE; ++pos) {
        int p = p0 + pos;
        float emb = bev[p]*bw0 + bev[PBEV + p]*bw1 + bb - cemb;
        float ss = blockSum128(emb * emb, red, t);
        float qv = emb / (sqrtf(ss) + 1e-7f) + x[(size_t)t * PBEV + p];
        query[((size_t)(n * PBEV + p)) * 128 + t] = qv;
    }
}

// ---------- MFMA 128x128 GEMM, 64 rows/block ----------
template<int LNF, int BIASF, int ADDM, int DUAL, int OUTBF, int QSCL>
__global__ __launch_bounds__(256)
void k_gemm_mfma(const float* __restrict__ A, const float* __restrict__ W,
                 const float* __restrict__ bias, const float* __restrict__ addb,
                 const float* __restrict__ W2, const float* __restrict__ bias2,
                 void* __restrict__ out2v, void* __restrict__ outv) {
    __shared__ unsigned short Al[64 * 136];
    __shared__ unsigned short Wl[128 * 136];
    const int t = threadIdx.x;
    const int rb = blockIdx.x * 64;
    const int lane = t & 63, wv = t >> 6;
    const int la = lane & 15, g = lane >> 4;

    {
        int r = t >> 2, seg = t & 3;
        const float* ar = A + (size_t)(rb + r) * 128 + seg * 32;
        float v[32];
        #pragma unroll
        for (int j = 0; j < 8; ++j)
            *(float4*)&v[4 * j] = *(const float4*)&ar[4 * j];
        if constexpr (LNF) {
            float s = 0.f;
            #pragma unroll
            for (int j = 0; j < 32; ++j) s += v[j];
            s += __shfl_xor(s, 1); s += __shfl_xor(s, 2);
            float mu = s * (1.0f / 128.0f);
            float ss = 0.f;
            #pragma unroll
            for (int j = 0; j < 32; ++j) { float d = v[j] - mu; ss += d * d; }
            ss += __shfl_xor(ss, 1); ss += __shfl_xor(ss, 2);
            float rs = rsqrtf(ss * (1.0f / 128.0f) + LN_EPS);
            #pragma unroll
            for (int j = 0; j < 32; ++j) v[j] = (v[j] - mu) * rs;
        }
        #pragma unroll
        for (int j8 = 0; j8 < 4; ++j8) {
            u16x8 o;
            #pragma unroll
            for (int j = 0; j < 8; ++j) o[j] = f2bf(v[8 * j8 + j]);
            *(u16x8*)&Al[r * 136 + seg * 32 + 8 * j8] = o;
        }
    }

    #pragma unroll 1
    for (int set = 0; set <= DUAL; ++set) {
        const float* Wc = set ? W2 : W;
        const float* bc = set ? bias2 : bias;
        void* ocv = set ? out2v : outv;
        if (set) __syncthreads();
        #pragma unroll
        for (int i = 0; i < 8; ++i) {
            int chunk = i * 256 + t;
            int c = chunk >> 4, k8 = chunk & 15;
            float4 v0 = *(const float4*)&Wc[(size_t)c * 128 + k8 * 8];
            float4 v1 = *(const float4*)&Wc[(size_t)c * 128 + k8 * 8 + 4];
            u16x8 o = { f2bf(v0.x), f2bf(v0.y), f2bf(v0.z), f2bf(v0.w),
                        f2bf(v1.x), f2bf(v1.y), f2bf(v1.z), f2bf(v1.w) };
            *(u16x8*)&Wl[c * 136 + k8 * 8] = o;
        }
        __syncthreads();

        short8 af[4];
        #pragma unroll
        for (int ks = 0; ks < 4; ++ks)
            af[ks] = *(short8*)&Al[(wv * 16 + la) * 136 + ks * 32 + g * 8];

        #pragma unroll
        for (int ct = 0; ct < 8; ++ct) {
            f32x4 acc = (f32x4){0.f, 0.f, 0.f, 0.f};
            #pragma unroll
            for (int ks = 0; ks < 4; ++ks) {
                short8 bf = *(short8*)&Wl[(ct * 16 + la) * 136 + ks * 32 + g * 8];
                acc = __builtin_amdgcn_mfma_f32_16x16x32_bf16(af[ks], bf, acc, 0, 0, 0);
            }
            int col = ct * 16 + la;
            float bv = 0.f;
            if constexpr (BIASF) bv = bc[col];
            #pragma unroll
            for (int r = 0; r < 4; ++r) {
                int row = rb + wv * 16 + g * 4 + r;
                float v = acc[r] + bv;
                if constexpr (QSCL) v *= ATT_SCALE;
                if constexpr (ADDM) { if (set == 0) v += addb[(size_t)row * 128 + col]; }
                if constexpr (OUTBF) ((unsigned short*)ocv)[(size_t)row * 128 + col] = f2bf(v);
                else                 ((float*)ocv)[(size_t)row * 128 + col] = v;
            }
        }
    }
}

// ---------- fused MFMA MLP: out = X + W2.gelu(W1.(LN?)(X) + b1) + b2 ----------
template<int LNF>
__global__ __launch_bounds__(256)
void k_mlp_mfma(const float* __restrict__ X, const float* __restrict__ W1,
                const float* __restrict__ b1, const float* __restrict__ W2,
                const float* __restrict__ b2, float* __restrict__ out) {
    __shared__ unsigned short Al[16 * 136];
    __shared__ unsigned short Wl[128 * 72];   // 9216 u16 (>= 64*136=8704)
    __shared__ unsigned short Gl[16 * 264];
    const int t = threadIdx.x;
    const int rb = blockIdx.x * 16;
    const int lane = t & 63, wv = t >> 6;
    const int la = lane & 15, g = lane >> 4;

    // stage A (16 rows x 128), optional LN: thread -> (row t>>4, 8-col seg t&15)
    {
        int r = t >> 4, seg = t & 15;
        const float* ar = X + (size_t)(rb + r) * 128 + seg * 8;
        float v[8];
        *(float4*)&v[0] = *(const float4*)&ar[0];
        *(float4*)&v[4] = *(const float4*)&ar[4];
        if constexpr (LNF) {
            float s = 0.f;
            #pragma unroll
            for (int j = 0; j < 8; ++j) s += v[j];
            s += __shfl_xor(s, 1); s += __shfl_xor(s, 2);
            s += __shfl_xor(s, 4); s += __shfl_xor(s, 8);
            float mu = s * (1.0f / 128.0f);
            float ss = 0.f;
            #pragma unroll
            for (int j = 0; j < 8; ++j) { float d = v[j] - mu; ss += d * d; }
            ss += __shfl_xor(ss, 1); ss += __shfl_xor(ss, 2);
            ss += __shfl_xor(ss, 4); ss += __shfl_xor(ss, 8);
            float rs = rsqrtf(ss * (1.0f / 128.0f) + LN_EPS);
            #pragma unroll
            for (int j = 0; j < 8; ++j) v[j] = (v[j] - mu) * rs;
        }
        u16x8 o;
        #pragma unroll
        for (int j = 0; j < 8; ++j) o[j] = f2bf(v[j]);
        *(u16x8*)&Al[r * 136 + seg * 8] = o;
    }
    __syncthreads();

    short8 af[4];
    #pragma unroll
    for (int ks = 0; ks < 4; ++ks)
        af[ks] = *(short8*)&Al[la * 136 + ks * 32 + g * 8];

    // GEMM1: 4 chunks of 64 hidden cols; each wave does one 16x16 tile per chunk
    #pragma unroll 1
    for (int cc = 0; cc < 4; ++cc) {
        {
            int c = t >> 2, s2 = t & 3;   // c 0..63 local col, s2: 32-k seg
            const float* wr = W1 + (size_t)(cc * 64 + c) * 128 + s2 * 32;
            #pragma unroll
            for (int j8 = 0; j8 < 4; ++j8) {
                float4 v0 = *(const float4*)&wr[8 * j8];
                float4 v1 = *(const float4*)&wr[8 * j8 + 4];
                u16x8 o = { f2bf(v0.x), f2bf(v0.y), f2bf(v0.z), f2bf(v0.w),
                            f2bf(v1.x), f2bf(v1.y), f2bf(v1.z), f2bf(v1.w) };
                *(u16x8*)&Wl[c * 136 + s2 * 32 + 8 * j8] = o;
            }
        }
        __syncthreads();
        f32x4 acc = (f32x4){0.f, 0.f, 0.f, 0.f};
        #pragma unroll
        for (int ks = 0; ks < 4; ++ks) {
            short8 bf = *(short8*)&Wl[(wv * 16 + la) * 136 + ks * 32 + g * 8];
            acc = __builtin_amdgcn_mfma_f32_16x16x32_bf16(af[ks], bf, acc, 0, 0, 0);
        }
        int col = cc * 64 + wv * 16 + la;
        float bv = b1[col];
        #pragma unroll
        for (int r = 0; r < 4; ++r)
            Gl[(g * 4 + r) * 264 + col] = f2bf(gelu_f(acc[r] + bv));
        __syncthreads();
    }

    // GEMM2: out[16][128] = G[16][256] . W2^T, 4 k-chunks of 64
    f32x4 acc2[2];
    acc2[0] = (f32x4){0.f, 0.f, 0.f, 0.f};
    acc2[1] = (f32x4){0.f, 0.f, 0.f, 0.f};
    #pragma unroll 1
    for (int kc = 0; kc < 4; ++kc) {
        {
            int c = t >> 1, s2 = t & 1;   // c 0..127 out col, s2: 32-k seg
            const float* wr = W2 + (size_t)c * 256 + kc * 64 + s2 * 32;
            #pragma unroll
            for (int j8 = 0; j8 < 4; ++j8) {
                float4 v0 = *(const float4*)&wr[8 * j8];
                float4 v1 = *(const float4*)&wr[8 * j8 + 4];
                u16x8 o = { f2bf(v0.x), f2bf(v0.y), f2bf(v0.z), f2bf(v0.w),
                            f2bf(v1.x), f2bf(v1.y), f2bf(v1.z), f2bf(v1.w) };
                *(u16x8*)&Wl[c * 72 + s2 * 32 + 8 * j8] = o;
            }
        }
        __syncthreads();
        #pragma unroll
        for (int half = 0; half < 2; ++half) {
            short8 pf = *(short8*)&Gl[la * 264 + kc * 64 + half * 32 + g * 8];
            #pragma unroll
            for (int ct = 0; ct < 2; ++ct) {
                short8 bf = *(short8*)&Wl[((wv * 2 + ct) * 16 + la) * 72 + half * 32 + g * 8];
                acc2[ct] = __builtin_amdgcn_mfma_f32_16x16x32_bf16(pf, bf, acc2[ct], 0, 0, 0);
            }
        }
        __syncthreads();
    }
    #pragma unroll
    for (int ct = 0; ct < 2; ++ct) {
        int col = (wv * 2 + ct) * 16 + la;
        float bv = b2[col];
        #pragma unroll
        for (int r = 0; r < 4; ++r) {
            int row = rb + g * 4 + r;
            out[(size_t)row * 128 + col] = acc2[ct][r] + bv + X[(size_t)row * 128 + col];
        }
    }
}

// ---------- generic tiled f32 GEMM (256 threads) ----------
template<int NI, int NO, int NOT, int BR, int MR, int LNF, int BIASF, int ACT,
         int SCL, int ADDM, int STM, int ASCL, int DUAL, int WRLN, int OUTBF>
__global__ __launch_bounds__(256)
void k_gemm(const float* __restrict__ A, const float* __restrict__ W,
            const float* __restrict__ bias, const float* __restrict__ addb,
            const float* __restrict__ ascale, const float* __restrict__ W2,
            const float* __restrict__ bias2, void* __restrict__ out2v,
            float* __restrict__ aux, void* __restrict__ outv) {
    constexpr int CG = NO / 8;
    constexpr int RG = 256 / CG;
    static_assert(RG * MR == BR, "tile mismatch");
    __shared__ float a_lds[BR][NI + 4];
    __shared__ float w_lds[32][NO + 4];
    const int t  = threadIdx.x;
    const int rb = blockIdx.x * BR;
    const int co = blockIdx.y * NO;

    constexpr int AF4 = (BR * NI / 4) / 256;
    #pragma unroll
    for (int i = 0; i < AF4; ++i) {
        int f4 = i * 256 + t;
        int row = f4 / (NI / 4), q = f4 % (NI / 4);
        float4 v = *(const float4*)&A[(size_t)(rb + row) * NI + 4 * q];
        if constexpr (ASCL) {
            float4 sc = *(const float4*)&ascale[4 * q];
            v.x *= sc.x; v.y *= sc.y; v.z *= sc.z; v.w *= sc.w;
        }
        *(float4*)&a_lds[row][4 * q] = v;
    }
    __syncthreads();

    if constexpr (LNF) {
        constexpr int TPR = 256 / BR;
        constexpr int CPT = NI / TPR;
        int row = t / TPR, seg = t % TPR, base = seg * CPT;
        float sum = 0.f;
        #pragma unroll
        for (int j = 0; j < CPT / 4; ++j) {
            float4 v = *(float4*)&a_lds[row][base + 4 * j];
            sum += (v.x + v.y) + (v.z + v.w);
        }
        #pragma unroll
        for (int o = 1; o < TPR; o <<= 1) sum += __shfl_xor(sum, o, 64);
        float mu = sum * (1.0f / NI);
        float ss = 0.f;
        #pragma unroll
        for (int j = 0; j < CPT / 4; ++j) {
            float4 v = *(float4*)&a_lds[row][base + 4 * j];
            float a = v.x - mu, b = v.y - mu, c = v.z - mu, d = v.w - mu;
            ss += (a * a + b * b) + (c * c + d * d);
        }
        #pragma unroll
        for (int o = 1; o < TPR; o <<= 1) ss += __shfl_xor(ss, o, 64);
        float rs = rsqrtf(ss * (1.0f / NI) + LN_EPS);
        #pragma unroll
        for (int j = 0; j < CPT / 4; ++j) {
            float4 v = *(float4*)&a_lds[row][base + 4 * j];
            v.x = (v.x - mu) * rs; v.y = (v.y - mu) * rs;
            v.z = (v.z - mu) * rs; v.w = (v.w - mu) * rs;
            *(float4*)&a_lds[row][base + 4 * j] = v;
            if constexpr (WRLN) {
                if (blockIdx.y == 0)
                    *(float4*)&aux[(size_t)(rb + row) * NI + base + 4 * j] = v;
            }
        }
        __syncthreads();
    }

    const int cg = t % CG, rg = t / CG;
    const int c0 = cg * 8, r0 = rg * MR;
    constexpr int NCH = NI / 32;
    constexpr int WF4 = NO / 32;

    #pragma unroll 1
    for (int set = 0; set <= DUAL; ++set) {
        const float* Wc = set ? W2 : W;
        const float* bc = set ? bias2 : bias;
        void* ocv = set ? out2v : outv;
        float acc[MR][8];
        #pragma unroll
        for (int i = 0; i < MR; ++i)
            #pragma unroll
            for (int j = 0; j < 8; ++j) acc[i][j] = 0.f;

        #pragma unroll 1
        for (int ch = 0; ch < NCH; ++ch) {
            int k0 = ch * 32;
            if (ch || set) __syncthreads();
            #pragma unroll
            for (int i = 0; i < WF4; ++i) {
                int f4 = i * 256 + t;
                int c = f4 >> 3, kq = f4 & 7;
                float4 v = *(const float4*)&Wc[(size_t)(co + c) * NI + k0 + 4 * kq];
                w_lds[4 * kq + 0][c] = v.x; w_lds[4 * kq + 1][c] = v.y;
                w_lds[4 * kq + 2][c] = v.z; w_lds[4 * kq + 3][c] = v.w;
            }
            __syncthreads();
            #pragma unroll
            for (int kk = 0; kk < 32; ++kk) {
                float4 w0 = *(float4*)&w_lds[kk][c0];
                float4 w1 = *(float4*)&w_lds[kk][c0 + 4];
                #pragma unroll
                for (int i = 0; i < MR; ++i) {
                    float a = a_lds[r0 + i][k0 + kk];
                    acc[i][0] += a * w0.x; acc[i][1] += a * w0.y;
                    acc[i][2] += a * w0.z; acc[i][3] += a * w0.w;
                    acc[i][4] += a * w1.x; acc[i][5] += a * w1.y;
                    acc[i][6] += a * w1.z; acc[i][7] += a * w1.w;
                }
            }
        }

        float bi[8];
        if constexpr (BIASF) {
            #pragma unroll
            for (int j = 0; j < 8; ++j) bi[j] = bc[co + c0 + j];
        }
        #pragma unroll
        for (int i = 0; i < MR; ++i)
            #pragma unroll
            for (int j = 0; j < 8; ++j) {
                float v = acc[i][j];
                if constexpr (BIASF) v += bi[j];
                if constexpr (SCL == 1) v *= BN_S;
                if constexpr (SCL == 2) v *= ATT_SCALE;
                if constexpr (ACT)   v = gelu_f(v);
                acc[i][j] = v;
            }
        if constexpr (ADDM == 1) {
            if (set == 0) {
                #pragma unroll
                for (int i = 0; i < MR; ++i) {
                    float4 a0 = *(const float4*)&addb[(size_t)(rb + r0 + i) * NOT + co + c0];
                    float4 a1 = *(const float4*)&addb[(size_t)(rb + r0 + i) * NOT + co + c0 + 4];
                    acc[i][0] += a0.x; acc[i][1] += a0.y; acc[i][2] += a0.z; acc[i][3] += a0.w;
                    acc[i][4] += a1.x; acc[i][5] += a1.y; acc[i][6] += a1.z; acc[i][7] += a1.w;
                }
            }
        }
        if constexpr (ADDM == 2) {
            if (set == 0) {
                #pragma unroll
                for (int j = 0; j < 8; ++j)
                    #pragma unroll
                    for (int i = 0; i < MR; ++i)
                        acc[i][j] += addb[(size_t)(co + c0 + j) * PBEV + rb + r0 + i];
            }
        }
        if constexpr (STM == 0) {
            if constexpr (OUTBF) {
                unsigned short* ob = (unsigned short*)ocv;
                #pragma unroll
                for (int i = 0; i < MR; ++i) {
                    u16x8 o;
                    #pragma unroll
                    for (int j = 0; j < 8; ++j) o[j] = f2bf(acc[i][j]);
                    *(u16x8*)&ob[(size_t)(rb + r0 + i) * NOT + co + c0] = o;
                }
            } else {
                float* oc = (float*)ocv;
                #pragma unroll
                for (int i = 0; i < MR; ++i) {
                    float4 o0 = {acc[i][0], acc[i][1], acc[i][2], acc[i][3]};
                    float4 o1 = {acc[i][4], acc[i][5], acc[i][6], acc[i][7]};
                    *(float4*)&oc[(size_t)(rb + r0 + i) * NOT + co + c0]     = o0;
                    *(float4*)&oc[(size_t)(rb + r0 + i) * NOT + co + c0 + 4] = o1;
                }
            }
        } else {
            float* oc = (float*)ocv;
            #pragma unroll
            for (int j = 0; j < 8; ++j)
                #pragma unroll
                for (int i = 0; i < MR; ++i)
                    oc[(size_t)(co + c0 + j) * PBEV + rb + r0 + i] = acc[i][j];
        }
    }
}

// ---------- MFMA flash attention, max-free softmax (qh pre-scaled by ATT_SCALE) ----------
template<int MODE>
__global__ __launch_bounds__(MODE == 1 ? 512 : 256)
void k_attn_mfma(const unsigned short* __restrict__ qh, const unsigned short* __restrict__ kh,
                 const unsigned short* __restrict__ vh, float* __restrict__ aout) {
    constexpr int WAVES = (MODE == 1) ? 8 : 4;
    constexpr int QTPW  = (MODE == 1) ? 3 : 1;
    constexpr int T = WAVES * 64;
    const int l = blockIdx.x, m = blockIdx.y;
    const int xw = l >> 3, yw = l & 7;
    const int t = threadIdx.x;
    const int lane = t & 63, wv = t >> 6;
    const int la = lane & 15, g = lane >> 4;

    __shared__ unsigned short Kl[KROWS * 40];
    __shared__ unsigned short Vt[32 * 312];
    __shared__ unsigned short Pl[WAVES * QTPW * 640];

    for (int i = t; i < KROWS * 4; i += T) {
        int row = i >> 2, seg = i & 3;
        int n = row / 48, kk = row % 48;
        int k1 = kk / 12, k2 = kk % 12;
        int h, w;
        if (MODE == 1) { h = xw * 4 + k1;  w = yw * 12 + k2; }
        else           { h = k1 * 8 + xw;  w = k2 * 8 + yw;  }
        size_t src = ((size_t)(n * PIMG + h * FWW + w)) * 128 + m * DHD + seg * 8;
        short8 kv = *(const short8*)&kh[src];
        *(short8*)&Kl[row * 40 + seg * 8] = kv;
        short8 vv = *(const short8*)&vh[src];
        #pragma unroll
        for (int j = 0; j < 8; ++j)
            Vt[(seg * 8 + j) * 312 + row] = (unsigned short)vv[j];
    }

    short8 qf[QTPW];
    #pragma unroll
    for (int qt = 0; qt < QTPW; ++qt) {
        int q = (wv * QTPW + qt) * 16 + la;
        int row;
        if (MODE == 1) {
            int n = q >> 6, ww = q & 63;
            row = n * PBEV + (xw * 8 + (ww >> 3)) * 64 + yw * 8 + (ww & 7);
        } else {
            row = ((q >> 3) * 8 + xw) * 64 + (q & 7) * 8 + yw;
        }
        qf[qt] = *(const short8*)&qh[(size_t)row * 128 + m * DHD + g * 8];
    }
    __syncthreads();

    f32x4 acc[QTPW][2];
    float srow[QTPW][4];
    #pragma unroll
    for (int qt = 0; qt < QTPW; ++qt) {
        acc[qt][0] = (f32x4){0.f, 0.f, 0.f, 0.f};
        acc[qt][1] = (f32x4){0.f, 0.f, 0.f, 0.f};
        #pragma unroll
        for (int r = 0; r < 4; ++r) srow[qt][r] = 0.f;
    }
    unsigned short* Pw = Pl + wv * QTPW * 640;

    #pragma unroll 1
    for (int c = 0; c < 9; ++c) {
        const int kk0 = c * 32;
        short8 kf0 = *(short8*)&Kl[(kk0 + la) * 40 + g * 8];
        short8 kf1 = *(short8*)&Kl[(kk0 + 16 + la) * 40 + g * 8];
        f32x4 S[QTPW][2];
        #pragma unroll
        for (int qt = 0; qt < QTPW; ++qt) {
            S[qt][0] = __builtin_amdgcn_mfma_f32_16x16x32_bf16(qf[qt], kf0, (f32x4){0.f,0.f,0.f,0.f}, 0, 0, 0);
            S[qt][1] = __builtin_amdgcn_mfma_f32_16x16x32_bf16(qf[qt], kf1, (f32x4){0.f,0.f,0.f,0.f}, 0, 0, 0);
        }
        // max-free: P = exp(S); per-thread partial row sums, no cross-lane ops in loop
        #pragma unroll
        for (int qt = 0; qt < QTPW; ++qt) {
            #pragma unroll
            for (int r = 0; r < 4; ++r) {
                float pa = __expf(S[qt][0][r]);
                float pb = __expf(S[qt][1][r]);
                srow[qt][r] += pa + pb;
                int prow = g * 4 + r;
                Pw[qt * 640 + prow * 40 + la]      = f2bf(pa);
                Pw[qt * 640 + prow * 40 + 16 + la] = f2bf(pb);
            }
        }
        asm volatile("s_waitcnt lgkmcnt(0)" ::: "memory");
        __builtin_amdgcn_sched_barrier(0);
        short8 vf0 = *(short8*)&Vt[la * 312 + kk0 + g * 8];
        short8 vf1 = *(short8*)&Vt[(16 + la) * 312 + kk0 + g * 8];
        #pragma unroll
        for (int qt = 0; qt < QTPW; ++qt) {
            short8 pf = *(short8*)&Pw[qt * 640 + la * 40 + g * 8];
            acc[qt][0] = __builtin_amdgcn_mfma_f32_16x16x32_bf16(pf, vf0, acc[qt][0], 0, 0, 0);
            acc[qt][1] = __builtin_amdgcn_mfma_f32_16x16x32_bf16(pf, vf1, acc[qt][1], 0, 0, 0);
        }
    }

    #pragma unroll
    for (int qt = 0; qt < QTPW; ++qt) {
        #pragma unroll
        for (int r = 0; r < 4; ++r) {
            float s = srow[qt][r];
            s += __shfl_xor(s, 1);
            s += __shfl_xor(s, 2);
            s += __shfl_xor(s, 4);
            s += __shfl_xor(s, 8);
            float inv = 1.0f / s;
            int q = (wv * QTPW + qt) * 16 + g * 4 + r;
            size_t orow;
            if (MODE == 1) {
                int n = q >> 6, ww = q & 63;
                orow = (size_t)(l * 64 + ww) * 6 + n;
            } else {
                orow = (size_t)(((q >> 3) * 8 + xw) * 64 + (q & 7) * 8 + yw);
            }
            float* ap = aout + orow * 128 + m * DHD;
            ap[la]      = acc[qt][0][r] * inv;
            ap[16 + la] = acc[qt][1][r] * inv;
        }
    }
}

// ---------- mean over 6 views + window->hw permute ----------
__global__ void k_mean(const float* __restrict__ abuf, float* __restrict__ amean) {
    int t = threadIdx.x;
    for (int rr = 0; rr < 8; ++rr) {
        int hw = blockIdx.x * 8 + rr;
        int h = hw >> 6, w = hw & 63;
        int xw = h >> 3, w1 = h & 7, yw = w >> 3, w2 = w & 7;
        int l = xw * 8 + yw, ww = w1 * 8 + w2;
        const float* src = abuf + ((size_t)(l * 64 + ww)) * 6 * 128;
        float s = 0.f;
        #pragma unroll
        for (int n = 0; n < 6; ++n) s += src[n * 128 + t];
        amean[(size_t)hw * 128 + t] = s * (1.0f / 6.0f);
    }
}

// ---------- depthwise 3x3 + gelu + SE partials ----------
__global__ void k_dwconv(const float* __restrict__ ex, const float* __restrict__ dwgt,
                         float* __restrict__ dwout, float* __restrict__ separt) {
    const int TILE = 16;
    int ch = threadIdx.x;
    int hw0 = blockIdx.x * TILE;
    float wreg[9];
    #pragma unroll
    for (int i = 0; i < 9; ++i) wreg[i] = dwgt[ch * 9 + i];
    float sacc = 0.f;
    for (int ti = 0; ti < TILE; ++ti) {
        int hw = hw0 + ti;
        int h = hw >> 6, w = hw & 63;
        float s = 0.f;
        #pragma unroll
        for (int dy = -1; dy <= 1; ++dy) {
            int h2 = h + dy;
            if (h2 < 0 || h2 >= 64) continue;
            #pragma unroll
            for (int dx = -1; dx <= 1; ++dx) {
                int w2 = w + dx;
                if (w2 < 0 || w2 >= 64) continue;
                s += ex[((size_t)(h2 * 64 + w2)) * 512 + ch] * wreg[(dy + 1) * 3 + (dx + 1)];
            }
        }
        float o = gelu_f(s * BN_S);
        dwout[(size_t)hw * 512 + ch] = o;
        sacc += o;
    }
    separt[(size_t)blockIdx.x * 512 + ch] = sacc;
}

// ---------- SE reduce stage 1: [256][512] -> [16][512] ----------
__global__ void k_sered(const float* __restrict__ separt, float* __restrict__ separt2) {
    int t = threadIdx.x, bb = blockIdx.x;
    float s = 0.f;
    #pragma unroll
    for (int i = 0; i < 16; ++i)
        s += separt[(size_t)(bb * 16 + i) * 512 + t];
    separt2[(size_t)bb * 512 + t] = s;
}

// ---------- SE final ----------
__global__ void k_se(const float* __restrict__ separt2,
                     const float* __restrict__ s1w, const float* __restrict__ s1b,
                     const float* __restrict__ s2w, const float* __restrict__ s2b,
                     float* __restrict__ se) {
    __shared__ float mean[512];
    __shared__ float s1[32];
    int t = threadIdx.x;
    float s = 0.f;
    #pragma unroll
    for (int b = 0; b < 16; ++b) s += separt2[b * 512 + t];
    mean[t] = s * (1.0f / 4096.0f);
    __syncthreads();
    int u = t >> 4, seg = t & 15;
    float acc = 0.f;
    #pragma unroll
    for (int j = 0; j < 32; ++j) {
        int c = seg + 16 * j;
        acc += mean[c] * s1w[u * 512 + c];
    }
    acc += __shfl_xor(acc, 1); acc += __shfl_xor(acc, 2);
    acc += __shfl_xor(acc, 4); acc += __shfl_xor(acc, 8);
    if (seg == 0) s1[u] = gelu_f(acc + s1b[u]);
    __syncthreads();
    float a2 = s2b[t];
    #pragma unroll
    for (int j = 0; j < 32; ++j) a2 += s1[j] * s2w[t * 32 + j];
    se[t] = 1.0f / (1.0f + __expf(-a2));
}

extern "C" void kernel_launch(void* const* d_in, const int* in_sizes, int n_in,
                              void* d_out, int out_size, void* d_ws, size_t ws_size,
                              hipStream_t stream) {
    (void)in_sizes; (void)n_in; (void)out_size; (void)ws_size;
    const float* x      = (const float*)d_in[1];
    const float* feat   = (const float*)d_in[2];
    const float* I_inv  = (const float*)d_in[3];
    const float* E_inv  = (const float*)d_in[4];
    const float* bev    = (const float*)d_in[5];
    const float* fl_w   = (const float*)d_in[6];
    const float* fp_w   = (const float*)d_in[7];
    const float* be_w   = (const float*)d_in[8];
    const float* be_b   = (const float*)d_in[9];
    const float* ie_w   = (const float*)d_in[10];
    const float* ce_w   = (const float*)d_in[11];
    const float* a1_qw  = (const float*)d_in[12];
    const float* a1_qb  = (const float*)d_in[13];
    const float* a1_kw  = (const float*)d_in[14];
    const float* a1_kb  = (const float*)d_in[15];
    const float* a1_vw  = (const float*)d_in[16];
    const float* a1_vb  = (const float*)d_in[17];
    const float* a1_pw  = (const float*)d_in[18];
    const float* a1_pb  = (const float*)d_in[19];
    const float* a2_qw  = (const float*)d_in[20];
    const float* a2_qb  = (const float*)d_in[21];
    const float* a2_kw  = (const float*)d_in[22];
    const float* a2_kb  = (const float*)d_in[23];
    const float* a2_vw  = (const float*)d_in[24];
    const float* a2_vb  = (const float*)d_in[25];
    const float* a2_pw  = (const float*)d_in[26];
    const float* a2_pb  = (const float*)d_in[27];
    const float* m1_w1  = (const float*)d_in[28];
    const float* m1_b1  = (const float*)d_in[29];
    const float* m1_w2  = (const float*)d_in[30];
    const float* m1_b2  = (const float*)d_in[31];
    const float* m2_w1  = (const float*)d_in[32];
    const float* m2_b1  = (const float*)d_in[33];
    const float* m2_w2  = (const float*)d_in[34];
    const float* m2_b2  = (const float*)d_in[35];
    const float* mb_ew  = (const float*)d_in[36];
    const float* mb_dw  = (const float*)d_in[37];
    const float* mb_s1w = (const float*)d_in[38];
    const float* mb_s1b = (const float*)d_in[39];
    const float* mb_s2w = (const float*)d_in[40];
    const float* mb_s2b = (const float*)d_in[41];
    const float* mb_pw  = (const float*)d_in[42];
    const float* pm_w1  = (const float*)d_in[43];
    const float* pm_b1  = (const float*)d_in[44];
    const float* pm_w2  = (const float*)d_in[45];
    const float* pm_b2  = (const float*)d_in[46];
    const float* po_w   = (const float*)d_in[47];
    const float* po_b   = (const float*)d_in[48];

    float* ws = (float*)d_ws;
    float* S0 = ws + 0;         // query -> abuf -> expandb
    float* S1 = ws + 3145728;   // qh1b -> qh2b -> dwout+separt+separt2+sebuf
    float* S2 = ws + 6291456;   // f_cl -> kh1b
    float* S3 = ws + 8650752;   // kinit -> vh1b
    float* S4 = ws + 11010048;  // key -> kh2b (in-place)
    float* S5 = ws + 13369344;  // val -> vh2b (in-place)
    float* amean  = ws + 15728640;
    float* qimg   = ws + 16252928;
    float* qimg2  = ws + 17825792;
    float* zln    = ws + 18350080;
    float* abuf2  = ws + 18874368;
    float* mbout  = ws + 19398656;

    float* f_cl  = S2;
    float* kinit = S3;
    float* key   = S4;
    float* val   = S5;
    float* query = S0;
    unsigned short* qh1b = (unsigned short*)S1;
    unsigned short* kh1b = (unsigned short*)S2;
    unsigned short* vh1b = (unsigned short*)S3;
    unsigned short* kh2b = (unsigned short*)S4;
    unsigned short* vh2b = (unsigned short*)S5;
    float* abuf  = S0;
    unsigned short* qh2b = (unsigned short*)S1;
    float* expandb = S0;
    float* dwout   = S1;
    float* separt  = S1 + 2097152;
    float* separt2 = S1 + 2097152 + 131072;
    float* sebuf   = S1 + 2097152 + 131072 + 8192;

    // stage 0: layout transforms + embeddings
    k_trans<<<dim3(96, 4, 6), 256, 0, stream>>>(feat, f_cl);
    k_embed<<<dim3(192, 6), 128, 0, stream>>>(I_inv, E_inv, ie_w, ce_w, kinit);
    k_query<<<dim3(256, 6), 128, 0, stream>>>(x, bev, be_w, be_b, E_inv, ce_w, query);
    k_gemm_mfma<0,0,1,1,0,0><<<288, 256, 0, stream>>>(
        f_cl, fp_w, nullptr, kinit, fl_w, nullptr, val, key);

    // stage 1: q/k/v heads -> bf16 (q pre-scaled by ATT_SCALE)
    k_gemm_mfma<1,1,0,0,1,1><<<384, 256, 0, stream>>>(
        query, a1_qw, a1_qb, nullptr, nullptr, nullptr, nullptr, qh1b);
    k_gemm_mfma<1,1,0,1,1,0><<<288, 256, 0, stream>>>(
        key, a1_kw, a1_kb, nullptr, a2_kw, a2_kb, kh2b, kh1b);
    k_gemm_mfma<1,1,0,1,1,0><<<288, 256, 0, stream>>>(
        val, a1_vw, a1_vb, nullptr, a2_vw, a2_vb, vh2b, vh1b);
    k_attn_mfma<1><<<dim3(64, HEADS), 512, 0, stream>>>(qh1b, kh1b, vh1b, abuf);
    k_mean<<<512, 128, 0, stream>>>(abuf, amean);
    k_gemm<128,128,128,16,1, 0,1,0,0, 2,0,0, 0,0,0><<<256, 256, 0, stream>>>(
        amean, a1_pw, a1_pb, x, nullptr, nullptr, nullptr, nullptr, nullptr, qimg);
    k_mlp_mfma<1><<<256, 256, 0, stream>>>(qimg, m1_w1, m1_b1, m1_w2, m1_b2, qimg);

    // stage 2: attn2 + MLP2
    k_gemm<128,128,128,16,1, 1,1,0,2, 0,0,0, 0,0,1><<<256, 256, 0, stream>>>(
        qimg, a2_qw, a2_qb, nullptr, nullptr, nullptr, nullptr, nullptr, nullptr, qh2b);
    k_attn_mfma<2><<<dim3(64, HEADS), 256, 0, stream>>>(qh2b, kh2b, vh2b, abuf2);
    k_gemm<128,128,128,16,1, 0,1,0,0, 1,0,0, 0,0,0><<<256, 256, 0, stream>>>(
        abuf2, a2_pw, a2_pb, qimg, nullptr, nullptr, nullptr, nullptr, nullptr, qimg2);
    k_mlp_mfma<1><<<256, 256, 0, stream>>>(qimg2, m2_w1, m2_b1, m2_w2, m2_b2, qimg2);

    // stage 3: postnorm(LN fused into expand) + MBConv + FFN + proj_out
    k_gemm<128,128,512,32,2, 1,0,1,1, 0,0,0, 0,1,0><<<dim3(128, 4), 256, 0, stream>>>(
        qimg2, mb_ew, nullptr, nullptr, nullptr, nullptr, nullptr, nullptr, zln, expandb);
    k_dwconv<<<256, 512, 0, stream>>>(expandb, mb_dw, dwout, separt);
    k_sered<<<16, 512, 0, stream>>>(separt, separt2);
    k_se<<<1, 512, 0, stream>>>(separt2, mb_s1w, mb_s1b, mb_s2w, mb_s2b, sebuf);
    k_gemm<512,128,128,16,1, 0,0,0,1, 1,0,1, 0,0,0><<<256, 256, 0, stream>>>(
        dwout, mb_pw, nullptr, zln, sebuf, nullptr, nullptr, nullptr, nullptr, mbout);
    k_mlp_mfma<0><<<256, 256, 0, stream>>>(mbout, pm_w1, pm_b1, pm_w2, pm_b2, mbout);
    k_gemm<128,128,128,16,1, 0,1,1,0, 0,1,0, 0,0,0><<<256, 256, 0, stream>>>(
        mbout, po_w, po_b, nullptr, nullptr, nullptr, nullptr, nullptr, nullptr, (float*)d_out);
}

// Round 9
// 215.623 us; speedup vs baseline: 1.2761x; 1.2761x over previous
//
#include <hip/hip_runtime.h>
#include <math.h>

#define NV 6
#define FHH 32
#define FWW 96
#define PIMG (FHH*FWW)   // 3072
#define HH 64
#define WWD 64
#define PBEV (HH*WWD)    // 4096
#define HEADS 4
#define DHD 32
#define KROWS 288
#define BN_S 0.9999950000374996f
#define LN_EPS 1e-5f
#define ATT_SCALE 0.17677669529663687f  // 32^-0.5

typedef __attribute__((ext_vector_type(8))) short short8;
typedef __attribute__((ext_vector_type(4))) float f32x4;
typedef __attribute__((ext_vector_type(8))) unsigned short u16x8;

__device__ __forceinline__ float gelu_f(float x) {
    return 0.5f * x * (1.0f + erff(x * 0.70710678118654752f));
}

__device__ __forceinline__ unsigned short f2bf(float f) {
    union { float f; unsigned int u; } c; c.f = f;
    unsigned int r = (c.u + 0x7fffu + ((c.u >> 16) & 1u)) >> 16;
    return (unsigned short)r;
}

__device__ __forceinline__ float blockSum128(float v, float* red, int tid) {
    #pragma unroll
    for (int o = 32; o > 0; o >>= 1) v += __shfl_down(v, o, 64);
    __syncthreads();
    if ((tid & 63) == 0) red[tid >> 6] = v;
    __syncthreads();
    return red[0] + red[1];
}

// ---------- geometric image embedding -> kinit [n*3072][128] ----------
__global__ void k_embed(const float* __restrict__ I_inv, const float* __restrict__ E_inv,
                        const float* __restrict__ ie_w, const float* __restrict__ ce_w,
                        float* __restrict__ kinit) {
    const int TILE = 16;
    int n = blockIdx.y, p0 = blockIdx.x * TILE, t = threadIdx.x;
    __shared__ float red[2];
    const float* E  = E_inv + n * 16;
    const float* Ii = I_inv + n * 9;
    float cemb = E[3]  * ce_w[t*4+0] + E[7]  * ce_w[t*4+1]
               + E[11] * ce_w[t*4+2] + E[15] * ce_w[t*4+3];
    for (int pos = 0; pos < TILE; ++pos) {
        int p = p0 + pos;
        int h = p / FWW, w = p % FWW;
        float gx = (float)w * (768.0f / 95.0f);
        float gy = (float)h * (256.0f / 31.0f);
        float c0 = Ii[0]*gx + Ii[1]*gy + Ii[2];
        float c1 = Ii[3]*gx + Ii[4]*gy + Ii[5];
        float c2 = Ii[6]*gx + Ii[7]*gy + Ii[8];
        float d0 = E[0]*c0  + E[1]*c1  + E[2]*c2  + E[3];
        float d1 = E[4]*c0  + E[5]*c1  + E[6]*c2  + E[7];
        float d2 = E[8]*c0  + E[9]*c1  + E[10]*c2 + E[11];
        float d3 = E[12]*c0 + E[13]*c1 + E[14]*c2 + E[15];
        float emb = d0*ie_w[t*4+0] + d1*ie_w[t*4+1]
                  + d2*ie_w[t*4+2] + d3*ie_w[t*4+3] - cemb;
        float ss = blockSum128(emb * emb, red, t);
        kinit[((size_t)(n * PIMG + p)) * 128 + t] = emb / (sqrtf(ss) + 1e-7f);
    }
}

// ---------- query [n*4096][128] ----------
__global__ void k_query(const float* __restrict__ x, const float* __restrict__ bev,
                        const float* __restrict__ be_w, const float* __restrict__ be_b,
                        const float* __restrict__ E_inv, const float* __restrict__ ce_w,
                        float* __restrict__ query) {
    const int TILE = 16;
    int n = blockIdx.y, p0 = blockIdx.x * TILE, t = threadIdx.x;
    __shared__ float red[2];
    const float* E = E_inv + n * 16;
    float cemb = E[3]  * ce_w[t*4+0] + E[7]  * ce_w[t*4+1]
               + E[11] * ce_w[t*4+2] + E[15] * ce_w[t*4+3];
    float bw0 = be_w[t*2+0], bw1 = be_w[t*2+1], bb = be_b[t];
    for (int pos = 0; pos < TILE; ++pos) {
        int p = p0 + pos;
        float emb = bev[p]*bw0 + bev[PBEV + p]*bw1 + bb - cemb;
        float ss = blockSum128(emb * emb, red, t);
        float qv = emb / (sqrtf(ss) + 1e-7f) + x[(size_t)t * PBEV + p];
        query[((size_t)(n * PBEV + p)) * 128 + t] = qv;
    }
}

// ---------- universal MFMA GEMM ----------
// BR rows/block (16 or 64), KCH k-chunks of 128 (NI=KCH*128), NOT = total out cols.
// col panel co = blockIdx.y*128.
// AMODE: 0 row-major f32 A; 1 feature [n][128][3072] transpose+BN+relu; 2 mean-6 of abuf.
// ADDM: 1 addb[row*128+col]; 2 addb[col*4096+row]. STM: 1 transposed f32 store.
// epilogue order: +bias, *BN_S(SCL), gelu(ACT), *ATT_SCALE(QSCL), +add, store.
template<int BR, int KCH, int NOT, int AMODE, int LNF, int BIASF, int ACT, int SCL,
         int ADDM, int STM, int ASCL, int DUAL, int OUTBF, int QSCL, int WRLN>
__global__ __launch_bounds__(256)
void k_gemm_mfma(const float* __restrict__ A, const float* __restrict__ W,
                 const float* __restrict__ bias, const float* __restrict__ addb,
                 const float* __restrict__ ascale, const float* __restrict__ W2,
                 const float* __restrict__ bias2, void* __restrict__ out2v,
                 float* __restrict__ aux, void* __restrict__ outv) {
    constexpr int NI = KCH * 128;
    constexpr int RW = BR / 16;     // row-wave count
    constexpr int CT = 8 / (4 / RW); // col tiles per wave
    __shared__ unsigned short Al[BR * 136];
    __shared__ unsigned short Wl[128 * 136];
    const int t = threadIdx.x;
    const int rb = blockIdx.x * BR;
    const int co = blockIdx.y * 128;
    const int lane = t & 63, wv = t >> 6;
    const int la = lane & 15, g = lane >> 4;
    const int roww = wv % RW, colg = wv / RW;

    // ---- stage A (KCH==1: full row, with LN / special modes) ----
    if constexpr (KCH == 1) {
        if constexpr (AMODE == 1) {
            // BR must be 64; A = feature [n][128][3072], fuse transpose+BN+relu
            int n = rb / PIMG, p0 = rb % PIMG;
            int r = t & 63, kseg = t >> 6;
            #pragma unroll
            for (int j8 = 0; j8 < 4; ++j8) {
                u16x8 o;
                #pragma unroll
                for (int j = 0; j < 8; ++j) {
                    int k = kseg * 32 + j8 * 8 + j;
                    float v = A[((size_t)(n * 128 + k)) * PIMG + p0 + r];
                    o[j] = f2bf(fmaxf(v * BN_S, 0.0f));
                }
                *(u16x8*)&Al[r * 136 + kseg * 32 + j8 * 8] = o;
            }
        } else {
            constexpr int TPR = 256 / BR;
            constexpr int CPT = 128 / TPR;
            int r = t / TPR, seg = t % TPR;
            float v[CPT];
            if constexpr (AMODE == 2) {
                int hw = rb + r;
                int h = hw >> 6, w = hw & 63;
                int l = (h >> 3) * 8 + (w >> 3), ww = (h & 7) * 8 + (w & 7);
                const float* src = A + ((size_t)(l * 64 + ww)) * 6 * 128 + seg * CPT;
                #pragma unroll
                for (int j = 0; j < CPT; ++j) v[j] = 0.f;
                #pragma unroll
                for (int n = 0; n < 6; ++n)
                    #pragma unroll
                    for (int j4 = 0; j4 < CPT / 4; ++j4) {
                        float4 x4 = *(const float4*)&src[n * 128 + 4 * j4];
                        v[4*j4]   += x4.x; v[4*j4+1] += x4.y;
                        v[4*j4+2] += x4.z; v[4*j4+3] += x4.w;
                    }
                #pragma unroll
                for (int j = 0; j < CPT; ++j) v[j] *= (1.0f / 6.0f);
            } else {
                const float* ar = A + (size_t)(rb + r) * 128 + seg * CPT;
                #pragma unroll
                for (int j4 = 0; j4 < CPT / 4; ++j4)
                    *(float4*)&v[4 * j4] = *(const float4*)&ar[4 * j4];
            }
            if constexpr (LNF) {
                float s = 0.f;
                #pragma unroll
                for (int j = 0; j < CPT; ++j) s += v[j];
                #pragma unroll
                for (int o = 1; o < TPR; o <<= 1) s += __shfl_xor(s, o, 64);
                float mu = s * (1.0f / 128.0f);
                float ss = 0.f;
                #pragma unroll
                for (int j = 0; j < CPT; ++j) { float d = v[j] - mu; ss += d * d; }
                #pragma unroll
                for (int o = 1; o < TPR; o <<= 1) ss += __shfl_xor(ss, o, 64);
                float rs = rsqrtf(ss * (1.0f / 128.0f) + LN_EPS);
                #pragma unroll
                for (int j = 0; j < CPT; ++j) v[j] = (v[j] - mu) * rs;
                if constexpr (WRLN) {
                    if (blockIdx.y == 0) {
                        #pragma unroll
                        for (int j4 = 0; j4 < CPT / 4; ++j4) {
                            float4 o4 = {v[4*j4], v[4*j4+1], v[4*j4+2], v[4*j4+3]};
                            *(float4*)&aux[(size_t)(rb + r) * 128 + seg * CPT + 4 * j4] = o4;
                        }
                    }
                }
            }
            #pragma unroll
            for (int j8 = 0; j8 < CPT / 8; ++j8) {
                u16x8 o;
                #pragma unroll
                for (int j = 0; j < 8; ++j) o[j] = f2bf(v[8 * j8 + j]);
                *(u16x8*)&Al[r * 136 + seg * CPT + 8 * j8] = o;
            }
        }
    }

    #pragma unroll 1
    for (int set = 0; set <= DUAL; ++set) {
        const float* Wc = set ? W2 : W;
        const float* bc = set ? bias2 : bias;
        void* ocv = set ? out2v : outv;
        f32x4 acc[CT];
        #pragma unroll
        for (int i = 0; i < CT; ++i) acc[i] = (f32x4){0.f, 0.f, 0.f, 0.f};

        #pragma unroll 1
        for (int kc = 0; kc < KCH; ++kc) {
            if (set || kc) __syncthreads();
            if constexpr (KCH > 1) {
                constexpr int TPR = 256 / BR;
                constexpr int CPT = 128 / TPR;
                int r = t / TPR, seg = t % TPR;
                const float* ar = A + (size_t)(rb + r) * NI + kc * 128 + seg * CPT;
                #pragma unroll
                for (int j8 = 0; j8 < CPT / 8; ++j8) {
                    float4 v0 = *(const float4*)&ar[8 * j8];
                    float4 v1 = *(const float4*)&ar[8 * j8 + 4];
                    if constexpr (ASCL) {
                        const float* sc = ascale + kc * 128 + seg * CPT + 8 * j8;
                        v0.x *= sc[0]; v0.y *= sc[1]; v0.z *= sc[2]; v0.w *= sc[3];
                        v1.x *= sc[4]; v1.y *= sc[5]; v1.z *= sc[6]; v1.w *= sc[7];
                    }
                    u16x8 o = { f2bf(v0.x), f2bf(v0.y), f2bf(v0.z), f2bf(v0.w),
                                f2bf(v1.x), f2bf(v1.y), f2bf(v1.z), f2bf(v1.w) };
                    *(u16x8*)&Al[r * 136 + seg * CPT + 8 * j8] = o;
                }
            }
            #pragma unroll
            for (int i = 0; i < 8; ++i) {
                int chunk = i * 256 + t;
                int c = chunk >> 4, k8 = chunk & 15;
                const float* wr = &Wc[(size_t)(co + c) * NI + kc * 128 + k8 * 8];
                float4 v0 = *(const float4*)&wr[0];
                float4 v1 = *(const float4*)&wr[4];
                u16x8 o = { f2bf(v0.x), f2bf(v0.y), f2bf(v0.z), f2bf(v0.w),
                            f2bf(v1.x), f2bf(v1.y), f2bf(v1.z), f2bf(v1.w) };
                *(u16x8*)&Wl[c * 136 + k8 * 8] = o;
            }
            __syncthreads();
            short8 af[4];
            #pragma unroll
            for (int ks = 0; ks < 4; ++ks)
                af[ks] = *(short8*)&Al[(roww * 16 + la) * 136 + ks * 32 + g * 8];
            #pragma unroll
            for (int cti = 0; cti < CT; ++cti) {
                int ct = colg * CT + cti;
                #pragma unroll
                for (int ks = 0; ks < 4; ++ks) {
                    short8 bf = *(short8*)&Wl[(ct * 16 + la) * 136 + ks * 32 + g * 8];
                    acc[cti] = __builtin_amdgcn_mfma_f32_16x16x32_bf16(af[ks], bf, acc[cti], 0, 0, 0);
                }
            }
        }

        #pragma unroll
        for (int cti = 0; cti < CT; ++cti) {
            int ct = colg * CT + cti;
            int col = co + ct * 16 + la;
            float bv = 0.f;
            if constexpr (BIASF) bv = bc[col];
            if constexpr (STM == 1) {
                int row0 = rb + roww * 16 + g * 4;
                float vv[4];
                #pragma unroll
                for (int r = 0; r < 4; ++r) {
                    float v = acc[cti][r] + bv;
                    if constexpr (SCL)  v *= BN_S;
                    if constexpr (ACT)  v = gelu_f(v);
                    if constexpr (QSCL) v *= ATT_SCALE;
                    vv[r] = v;
                }
                float4 o4 = {vv[0], vv[1], vv[2], vv[3]};
                *(float4*)&((float*)ocv)[(size_t)col * PBEV + row0] = o4;
            } else {
                #pragma unroll
                for (int r = 0; r < 4; ++r) {
                    int row = rb + roww * 16 + g * 4 + r;
                    float v = acc[cti][r] + bv;
                    if constexpr (SCL)  v *= BN_S;
                    if constexpr (ACT)  v = gelu_f(v);
                    if constexpr (QSCL) v *= ATT_SCALE;
                    if constexpr (ADDM == 1) { if (set == 0) v += addb[(size_t)row * 128 + col]; }
                    if constexpr (ADDM == 2) { if (set == 0) v += addb[(size_t)col * PBEV + row]; }
                    if constexpr (OUTBF) ((unsigned short*)ocv)[(size_t)row * NOT + col] = f2bf(v);
                    else                 ((float*)ocv)[(size_t)row * NOT + col] = v;
                }
            }
        }
    }
}

// ---------- fused MFMA MLP: out = X + W2.gelu(W1.(LN?)(X) + b1) + b2 ----------
template<int LNF>
__global__ __launch_bounds__(256)
void k_mlp_mfma(const float* __restrict__ X, const float* __restrict__ W1,
                const float* __restrict__ b1, const float* __restrict__ W2,
                const float* __restrict__ b2, float* __restrict__ out) {
    __shared__ unsigned short Al[16 * 136];
    __shared__ unsigned short Wl[128 * 72];
    __shared__ unsigned short Gl[16 * 264];
    const int t = threadIdx.x;
    const int rb = blockIdx.x * 16;
    const int lane = t & 63, wv = t >> 6;
    const int la = lane & 15, g = lane >> 4;

    {
        int r = t >> 4, seg = t & 15;
        const float* ar = X + (size_t)(rb + r) * 128 + seg * 8;
        float v[8];
        *(float4*)&v[0] = *(const float4*)&ar[0];
        *(float4*)&v[4] = *(const float4*)&ar[4];
        if constexpr (LNF) {
            float s = 0.f;
            #pragma unroll
            for (int j = 0; j < 8; ++j) s += v[j];
            s += __shfl_xor(s, 1); s += __shfl_xor(s, 2);
            s += __shfl_xor(s, 4); s += __shfl_xor(s, 8);
            float mu = s * (1.0f / 128.0f);
            float ss = 0.f;
            #pragma unroll
            for (int j = 0; j < 8; ++j) { float d = v[j] - mu; ss += d * d; }
            ss += __shfl_xor(ss, 1); ss += __shfl_xor(ss, 2);
            ss += __shfl_xor(ss, 4); ss += __shfl_xor(ss, 8);
            float rs = rsqrtf(ss * (1.0f / 128.0f) + LN_EPS);
            #pragma unroll
            for (int j = 0; j < 8; ++j) v[j] = (v[j] - mu) * rs;
        }
        u16x8 o;
        #pragma unroll
        for (int j = 0; j < 8; ++j) o[j] = f2bf(v[j]);
        *(u16x8*)&Al[r * 136 + seg * 8] = o;
    }
    __syncthreads();

    short8 af[4];
    #pragma unroll
    for (int ks = 0; ks < 4; ++ks)
        af[ks] = *(short8*)&Al[la * 136 + ks * 32 + g * 8];

    #pragma unroll 1
    for (int cc = 0; cc < 4; ++cc) {
        {
            int c = t >> 2, s2 = t & 3;
            const float* wr = W1 + (size_t)(cc * 64 + c) * 128 + s2 * 32;
            #pragma unroll
            for (int j8 = 0; j8 < 4; ++j8) {
                float4 v0 = *(const float4*)&wr[8 * j8];
                float4 v1 = *(const float4*)&wr[8 * j8 + 4];
                u16x8 o = { f2bf(v0.x), f2bf(v0.y), f2bf(v0.z), f2bf(v0.w),
                            f2bf(v1.x), f2bf(v1.y), f2bf(v1.z), f2bf(v1.w) };
                *(u16x8*)&Wl[c * 136 + s2 * 32 + 8 * j8] = o;
            }
        }
        __syncthreads();
        f32x4 acc = (f32x4){0.f, 0.f, 0.f, 0.f};
        #pragma unroll
        for (int ks = 0; ks < 4; ++ks) {
            short8 bf = *(short8*)&Wl[(wv * 16 + la) * 136 + ks * 32 + g * 8];
            acc = __builtin_amdgcn_mfma_f32_16x16x32_bf16(af[ks], bf, acc, 0, 0, 0);
        }
        int col = cc * 64 + wv * 16 + la;
        float bv = b1[col];
        #pragma unroll
        for (int r = 0; r < 4; ++r)
            Gl[(g * 4 + r) * 264 + col] = f2bf(gelu_f(acc[r] + bv));
        __syncthreads();
    }

    f32x4 acc2[2];
    acc2[0] = (f32x4){0.f, 0.f, 0.f, 0.f};
    acc2[1] = (f32x4){0.f, 0.f, 0.f, 0.f};
    #pragma unroll 1
    for (int kc = 0; kc < 4; ++kc) {
        {
            int c = t >> 1, s2 = t & 1;
            const float* wr = W2 + (size_t)c * 256 + kc * 64 + s2 * 32;
            #pragma unroll
            for (int j8 = 0; j8 < 4; ++j8) {
                float4 v0 = *(const float4*)&wr[8 * j8];
                float4 v1 = *(const float4*)&wr[8 * j8 + 4];
                u16x8 o = { f2bf(v0.x), f2bf(v0.y), f2bf(v0.z), f2bf(v0.w),
                            f2bf(v1.x), f2bf(v1.y), f2bf(v1.z), f2bf(v1.w) };
                *(u16x8*)&Wl[c * 72 + s2 * 32 + 8 * j8] = o;
            }
        }
        __syncthreads();
        #pragma unroll
        for (int half = 0; half < 2; ++half) {
            short8 pf = *(short8*)&Gl[la * 264 + kc * 64 + half * 32 + g * 8];
            #pragma unroll
            for (int ct = 0; ct < 2; ++ct) {
                short8 bf = *(short8*)&Wl[((wv * 2 + ct) * 16 + la) * 72 + half * 32 + g * 8];
                acc2[ct] = __builtin_amdgcn_mfma_f32_16x16x32_bf16(pf, bf, acc2[ct], 0, 0, 0);
            }
        }
        __syncthreads();
    }
    #pragma unroll
    for (int ct = 0; ct < 2; ++ct) {
        int col = (wv * 2 + ct) * 16 + la;
        float bv = b2[col];
        #pragma unroll
        for (int r = 0; r < 4; ++r) {
            int row = rb + g * 4 + r;
            out[(size_t)row * 128 + col] = acc2[ct][r] + bv + X[(size_t)row * 128 + col];
        }
    }
}

// ---------- MFMA flash attention, max-free softmax (qh pre-scaled by ATT_SCALE) ----------
template<int MODE>
__global__ __launch_bounds__(MODE == 1 ? 512 : 256)
void k_attn_mfma(const unsigned short* __restrict__ qh, const unsigned short* __restrict__ kh,
                 const unsigned short* __restrict__ vh, float* __restrict__ aout) {
    constexpr int WAVES = (MODE == 1) ? 8 : 4;
    constexpr int QTPW  = (MODE == 1) ? 3 : 1;
    constexpr int T = WAVES * 64;
    const int l = blockIdx.x, m = blockIdx.y;
    const int xw = l >> 3, yw = l & 7;
    const int t = threadIdx.x;
    const int lane = t & 63, wv = t >> 6;
    const int la = lane & 15, g = lane >> 4;

    __shared__ unsigned short Kl[KROWS * 40];
    __shared__ unsigned short Vt[32 * 312];
    __shared__ unsigned short Pl[WAVES * QTPW * 640];

    for (int i = t; i < KROWS * 4; i += T) {
        int row = i >> 2, seg = i & 3;
        int n = row / 48, kk = row % 48;
        int k1 = kk / 12, k2 = kk % 12;
        int h, w;
        if (MODE == 1) { h = xw * 4 + k1;  w = yw * 12 + k2; }
        else           { h = k1 * 8 + xw;  w = k2 * 8 + yw;  }
        size_t src = ((size_t)(n * PIMG + h * FWW + w)) * 128 + m * DHD + seg * 8;
        short8 kv = *(const short8*)&kh[src];
        *(short8*)&Kl[row * 40 + seg * 8] = kv;
        short8 vv = *(const short8*)&vh[src];
        #pragma unroll
        for (int j = 0; j < 8; ++j)
            Vt[(seg * 8 + j) * 312 + row] = (unsigned short)vv[j];
    }

    short8 qf[QTPW];
    #pragma unroll
    for (int qt = 0; qt < QTPW; ++qt) {
        int q = (wv * QTPW + qt) * 16 + la;
        int row;
        if (MODE == 1) {
            int n = q >> 6, ww = q & 63;
            row = n * PBEV + (xw * 8 + (ww >> 3)) * 64 + yw * 8 + (ww & 7);
        } else {
            row = ((q >> 3) * 8 + xw) * 64 + (q & 7) * 8 + yw;
        }
        qf[qt] = *(const short8*)&qh[(size_t)row * 128 + m * DHD + g * 8];
    }
    __syncthreads();

    f32x4 acc[QTPW][2];
    float srow[QTPW][4];
    #pragma unroll
    for (int qt = 0; qt < QTPW; ++qt) {
        acc[qt][0] = (f32x4){0.f, 0.f, 0.f, 0.f};
        acc[qt][1] = (f32x4){0.f, 0.f, 0.f, 0.f};
        #pragma unroll
        for (int r = 0; r < 4; ++r) srow[qt][r] = 0.f;
    }
    unsigned short* Pw = Pl + wv * QTPW * 640;

    #pragma unroll 1
    for (int c = 0; c < 9; ++c) {
        const int kk0 = c * 32;
        short8 kf0 = *(short8*)&Kl[(kk0 + la) * 40 + g * 8];
        short8 kf1 = *(short8*)&Kl[(kk0 + 16 + la) * 40 + g * 8];
        f32x4 S[QTPW][2];
        #pragma unroll
        for (int qt = 0; qt < QTPW; ++qt) {
            S[qt][0] = __builtin_amdgcn_mfma_f32_16x16x32_bf16(qf[qt], kf0, (f32x4){0.f,0.f,0.f,0.f}, 0, 0, 0);
            S[qt][1] = __builtin_amdgcn_mfma_f32_16x16x32_bf16(qf[qt], kf1, (f32x4){0.f,0.f,0.f,0.f}, 0, 0, 0);
        }
        #pragma unroll
        for (int qt = 0; qt < QTPW; ++qt) {
            #pragma unroll
            for (int r = 0; r < 4; ++r) {
                float pa = __expf(S[qt][0][r]);
                float pb = __expf(S[qt][1][r]);
                srow[qt][r] += pa + pb;
                int prow = g * 4 + r;
                Pw[qt * 640 + prow * 40 + la]      = f2bf(pa);
                Pw[qt * 640 + prow * 40 + 16 + la] = f2bf(pb);
            }
        }
        asm volatile("s_waitcnt lgkmcnt(0)" ::: "memory");
        __builtin_amdgcn_sched_barrier(0);
        short8 vf0 = *(short8*)&Vt[la * 312 + kk0 + g * 8];
        short8 vf1 = *(short8*)&Vt[(16 + la) * 312 + kk0 + g * 8];
        #pragma unroll
        for (int qt = 0; qt < QTPW; ++qt) {
            short8 pf = *(short8*)&Pw[qt * 640 + la * 40 + g * 8];
            acc[qt][0] = __builtin_amdgcn_mfma_f32_16x16x32_bf16(pf, vf0, acc[qt][0], 0, 0, 0);
            acc[qt][1] = __builtin_amdgcn_mfma_f32_16x16x32_bf16(pf, vf1, acc[qt][1], 0, 0, 0);
        }
    }

    #pragma unroll
    for (int qt = 0; qt < QTPW; ++qt) {
        #pragma unroll
        for (int r = 0; r < 4; ++r) {
            float s = srow[qt][r];
            s += __shfl_xor(s, 1);
            s += __shfl_xor(s, 2);
            s += __shfl_xor(s, 4);
            s += __shfl_xor(s, 8);
            float inv = 1.0f / s;
            int q = (wv * QTPW + qt) * 16 + g * 4 + r;
            size_t orow;
            if (MODE == 1) {
                int n = q >> 6, ww = q & 63;
                orow = (size_t)(l * 64 + ww) * 6 + n;
            } else {
                orow = (size_t)(((q >> 3) * 8 + xw) * 64 + (q & 7) * 8 + yw);
            }
            float* ap = aout + orow * 128 + m * DHD;
            ap[la]      = acc[qt][0][r] * inv;
            ap[16 + la] = acc[qt][1][r] * inv;
        }
    }
}

// ---------- depthwise 3x3 + gelu + SE partials ----------
__global__ void k_dwconv(const float* __restrict__ ex, const float* __restrict__ dwgt,
                         float* __restrict__ dwout, float* __restrict__ separt) {
    const int TILE = 16;
    int ch = threadIdx.x;
    int hw0 = blockIdx.x * TILE;
    float wreg[9];
    #pragma unroll
    for (int i = 0; i < 9; ++i) wreg[i] = dwgt[ch * 9 + i];
    float sacc = 0.f;
    for (int ti = 0; ti < TILE; ++ti) {
        int hw = hw0 + ti;
        int h = hw >> 6, w = hw & 63;
        float s = 0.f;
        #pragma unroll
        for (int dy = -1; dy <= 1; ++dy) {
            int h2 = h + dy;
            if (h2 < 0 || h2 >= 64) continue;
            #pragma unroll
            for (int dx = -1; dx <= 1; ++dx) {
                int w2 = w + dx;
                if (w2 < 0 || w2 >= 64) continue;
                s += ex[((size_t)(h2 * 64 + w2)) * 512 + ch] * wreg[(dy + 1) * 3 + (dx + 1)];
            }
        }
        float o = gelu_f(s * BN_S);
        dwout[(size_t)hw * 512 + ch] = o;
        sacc += o;
    }
    separt[(size_t)blockIdx.x * 512 + ch] = sacc;
}

// ---------- SE reduce stage 1: [256][512] -> [16][512] ----------
__global__ void k_sered(const float* __restrict__ separt, float* __restrict__ separt2) {
    int t = threadIdx.x, bb = blockIdx.x;
    float s = 0.f;
    #pragma unroll
    for (int i = 0; i < 16; ++i)
        s += separt[(size_t)(bb * 16 + i) * 512 + t];
    separt2[(size_t)bb * 512 + t] = s;
}

// ---------- SE final ----------
__global__ void k_se(const float* __restrict__ separt2,
                     const float* __restrict__ s1w, const float* __restrict__ s1b,
                     const float* __restrict__ s2w, const float* __restrict__ s2b,
                     float* __restrict__ se) {
    __shared__ float mean[512];
    __shared__ float s1[32];
    int t = threadIdx.x;
    float s = 0.f;
    #pragma unroll
    for (int b = 0; b < 16; ++b) s += separt2[b * 512 + t];
    mean[t] = s * (1.0f / 4096.0f);
    __syncthreads();
    int u = t >> 4, seg = t & 15;
    float acc = 0.f;
    #pragma unroll
    for (int j = 0; j < 32; ++j) {
        int c = seg + 16 * j;
        acc += mean[c] * s1w[u * 512 + c];
    }
    acc += __shfl_xor(acc, 1); acc += __shfl_xor(acc, 2);
    acc += __shfl_xor(acc, 4); acc += __shfl_xor(acc, 8);
    if (seg == 0) s1[u] = gelu_f(acc + s1b[u]);
    __syncthreads();
    float a2 = s2b[t];
    #pragma unroll
    for (int j = 0; j < 32; ++j) a2 += s1[j] * s2w[t * 32 + j];
    se[t] = 1.0f / (1.0f + __expf(-a2));
}

extern "C" void kernel_launch(void* const* d_in, const int* in_sizes, int n_in,
                              void* d_out, int out_size, void* d_ws, size_t ws_size,
                              hipStream_t stream) {
    (void)in_sizes; (void)n_in; (void)out_size; (void)ws_size;
    const float* x      = (const float*)d_in[1];
    const float* feat   = (const float*)d_in[2];
    const float* I_inv  = (const float*)d_in[3];
    const float* E_inv  = (const float*)d_in[4];
    const float* bev    = (const float*)d_in[5];
    const float* fl_w   = (const float*)d_in[6];
    const float* fp_w   = (const float*)d_in[7];
    const float* be_w   = (const float*)d_in[8];
    const float* be_b   = (const float*)d_in[9];
    const float* ie_w   = (const float*)d_in[10];
    const float* ce_w   = (const float*)d_in[11];
    const float* a1_qw  = (const float*)d_in[12];
    const float* a1_qb  = (const float*)d_in[13];
    const float* a1_kw  = (const float*)d_in[14];
    const float* a1_kb  = (const float*)d_in[15];
    const float* a1_vw  = (const float*)d_in[16];
    const float* a1_vb  = (const float*)d_in[17];
    const float* a1_pw  = (const float*)d_in[18];
    const float* a1_pb  = (const float*)d_in[19];
    const float* a2_qw  = (const float*)d_in[20];
    const float* a2_qb  = (const float*)d_in[21];
    const float* a2_kw  = (const float*)d_in[22];
    const float* a2_kb  = (const float*)d_in[23];
    const float* a2_vw  = (const float*)d_in[24];
    const float* a2_vb  = (const float*)d_in[25];
    const float* a2_pw  = (const float*)d_in[26];
    const float* a2_pb  = (const float*)d_in[27];
    const float* m1_w1  = (const float*)d_in[28];
    const float* m1_b1  = (const float*)d_in[29];
    const float* m1_w2  = (const float*)d_in[30];
    const float* m1_b2  = (const float*)d_in[31];
    const float* m2_w1  = (const float*)d_in[32];
    const float* m2_b1  = (const float*)d_in[33];
    const float* m2_w2  = (const float*)d_in[34];
    const float* m2_b2  = (const float*)d_in[35];
    const float* mb_ew  = (const float*)d_in[36];
    const float* mb_dw  = (const float*)d_in[37];
    const float* mb_s1w = (const float*)d_in[38];
    const float* mb_s1b = (const float*)d_in[39];
    const float* mb_s2w = (const float*)d_in[40];
    const float* mb_s2b = (const float*)d_in[41];
    const float* mb_pw  = (const float*)d_in[42];
    const float* pm_w1  = (const float*)d_in[43];
    const float* pm_b1  = (const float*)d_in[44];
    const float* pm_w2  = (const float*)d_in[45];
    const float* pm_b2  = (const float*)d_in[46];
    const float* po_w   = (const float*)d_in[47];
    const float* po_b   = (const float*)d_in[48];

    float* ws = (float*)d_ws;
    float* S0 = ws + 0;         // query -> abuf -> expandb
    float* S1 = ws + 3145728;   // qh1b -> qh2b -> dwout+separt+separt2+sebuf
    float* S2 = ws + 6291456;   // kh1b
    float* S3 = ws + 8650752;   // kinit -> vh1b
    float* S4 = ws + 11010048;  // key -> kh2b (in-place)
    float* S5 = ws + 13369344;  // val -> vh2b (in-place)
    float* qimg   = ws + 16252928;
    float* qimg2  = ws + 17825792;
    float* zln    = ws + 18350080;
    float* abuf2  = ws + 18874368;
    float* mbout  = ws + 19398656;

    float* kinit = S3;
    float* key   = S4;
    float* val   = S5;
    float* query = S0;
    unsigned short* qh1b = (unsigned short*)S1;
    unsigned short* kh1b = (unsigned short*)S2;
    unsigned short* vh1b = (unsigned short*)S3;
    unsigned short* kh2b = (unsigned short*)S4;
    unsigned short* vh2b = (unsigned short*)S5;
    float* abuf  = S0;
    unsigned short* qh2b = (unsigned short*)S1;
    float* expandb = S0;
    float* dwout   = S1;
    float* separt  = S1 + 2097152;
    float* separt2 = S1 + 2097152 + 131072;
    float* sebuf   = S1 + 2097152 + 131072 + 8192;

    // stage 0: embeddings + key/val (feature transpose fused into GEMM staging)
    k_embed<<<dim3(192, 6), 128, 0, stream>>>(I_inv, E_inv, ie_w, ce_w, kinit);
    k_query<<<dim3(256, 6), 128, 0, stream>>>(x, bev, be_w, be_b, E_inv, ce_w, query);
    k_gemm_mfma<64,1,128, 1,0,0,0,0, 1,0,0,1, 0,0,0><<<288, 256, 0, stream>>>(
        feat, fp_w, nullptr, kinit, nullptr, fl_w, nullptr, val, nullptr, key);

    // stage 1: q/k/v heads -> bf16 (q pre-scaled by ATT_SCALE); attn1; proj(+mean fused)
    k_gemm_mfma<64,1,128, 0,1,1,0,0, 0,0,0,0, 1,1,0><<<384, 256, 0, stream>>>(
        query, a1_qw, a1_qb, nullptr, nullptr, nullptr, nullptr, nullptr, nullptr, qh1b);
    k_gemm_mfma<64,1,128, 0,1,1,0,0, 0,0,0,1, 1,0,0><<<288, 256, 0, stream>>>(
        key, a1_kw, a1_kb, nullptr, nullptr, a2_kw, a2_kb, kh2b, nullptr, kh1b);
    k_gemm_mfma<64,1,128, 0,1,1,0,0, 0,0,0,1, 1,0,0><<<288, 256, 0, stream>>>(
        val, a1_vw, a1_vb, nullptr, nullptr, a2_vw, a2_vb, vh2b, nullptr, vh1b);
    k_attn_mfma<1><<<dim3(64, HEADS), 512, 0, stream>>>(qh1b, kh1b, vh1b, abuf);
    k_gemm_mfma<16,1,128, 2,0,1,0,0, 2,0,0,0, 0,0,0><<<256, 256, 0, stream>>>(
        abuf, a1_pw, a1_pb, x, nullptr, nullptr, nullptr, nullptr, nullptr, qimg);
    k_mlp_mfma<1><<<256, 256, 0, stream>>>(qimg, m1_w1, m1_b1, m1_w2, m1_b2, qimg);

    // stage 2: attn2 + MLP2
    k_gemm_mfma<16,1,128, 0,1,1,0,0, 0,0,0,0, 1,1,0><<<256, 256, 0, stream>>>(
        qimg, a2_qw, a2_qb, nullptr, nullptr, nullptr, nullptr, nullptr, nullptr, qh2b);
    k_attn_mfma<2><<<dim3(64, HEADS), 256, 0, stream>>>(qh2b, kh2b, vh2b, abuf2);
    k_gemm_mfma<16,1,128, 0,0,1,0,0, 1,0,0,0, 0,0,0><<<256, 256, 0, stream>>>(
        abuf2, a2_pw, a2_pb, qimg, nullptr, nullptr, nullptr, nullptr, nullptr, qimg2);
    k_mlp_mfma<1><<<256, 256, 0, stream>>>(qimg2, m2_w1, m2_b1, m2_w2, m2_b2, qimg2);

    // stage 3: postnorm LN fused into expand; MBConv; FFN; proj_out
    k_gemm_mfma<16,1,512, 0,1,0,1,1, 0,0,0,0, 0,0,1><<<dim3(256, 4), 256, 0, stream>>>(
        qimg2, mb_ew, nullptr, nullptr, nullptr, nullptr, nullptr, nullptr, zln, expandb);
    k_dwconv<<<256, 512, 0, stream>>>(expandb, mb_dw, dwout, separt);
    k_sered<<<16, 512, 0, stream>>>(separt, separt2);
    k_se<<<1, 512, 0, stream>>>(separt2, mb_s1w, mb_s1b, mb_s2w, mb_s2b, sebuf);
    k_gemm_mfma<16,4,128, 0,0,0,0,1, 1,0,1,0, 0,0,0><<<256, 256, 0, stream>>>(
        dwout, mb_pw, nullptr, zln, sebuf, nullptr, nullptr, nullptr, nullptr, mbout);
    k_mlp_mfma<0><<<256, 256, 0, stream>>>(mbout, pm_w1, pm_b1, pm_w2, pm_b2, mbout);
    k_gemm_mfma<16,1,128, 0,0,1,1,0, 0,1,0,0, 0,0,0><<<256, 256, 0, stream>>>(
        mbout, po_w, po_b, nullptr, nullptr, nullptr, nullptr, nullptr, nullptr, (float*)d_out);
}

// Round 10
// 197.597 us; speedup vs baseline: 1.3925x; 1.0912x over previous
//
#include <hip/hip_runtime.h>
#include <math.h>

#define NV 6
#define FHH 32
#define FWW 96
#define PIMG (FHH*FWW)   // 3072
#define HH 64
#define WWD 64
#define PBEV (HH*WWD)    // 4096
#define HEADS 4
#define DHD 32
#define KROWS 288
#define BN_S 0.9999950000374996f
#define LN_EPS 1e-5f
#define ATT_SCALE 0.17677669529663687f  // 32^-0.5

typedef __attribute__((ext_vector_type(8))) short short8;
typedef __attribute__((ext_vector_type(4))) float f32x4;
typedef __attribute__((ext_vector_type(8))) unsigned short u16x8;

__device__ __forceinline__ float gelu_f(float x) {
    return 0.5f * x * (1.0f + erff(x * 0.70710678118654752f));
}

__device__ __forceinline__ unsigned short f2bf(float f) {
    union { float f; unsigned int u; } c; c.f = f;
    unsigned int r = (c.u + 0x7fffu + ((c.u >> 16) & 1u)) >> 16;
    return (unsigned short)r;
}

__device__ __forceinline__ float bf2f(unsigned short u) {
    union { unsigned int u; float f; } c; c.u = ((unsigned int)u) << 16;
    return c.f;
}

// ---------- x transpose: [128][4096] -> [4096][128] ----------
__global__ void k_transx(const float* __restrict__ x, float* __restrict__ x_cl) {
    __shared__ float tile[32][33];
    int c0 = blockIdx.y * 32, p0 = blockIdx.x * 32;
    int tp = threadIdx.x & 31, tg = threadIdx.x >> 5;
    #pragma unroll
    for (int i = 0; i < 4; ++i)
        tile[tg + 8 * i][tp] = x[(size_t)(c0 + tg + 8 * i) * PBEV + p0 + tp];
    __syncthreads();
    #pragma unroll
    for (int i = 0; i < 4; ++i)
        x_cl[(size_t)(p0 + tg + 8 * i) * 128 + c0 + tp] = tile[tp][tg + 8 * i];
}

// ---------- universal MFMA GEMM ----------
// AMODE: 0 f32 row-major A; 1 feature [n][128][3072] (transpose+BN+relu);
//        2 mean-6 of abuf; 3 fused query gen (bev/x_cl/be/E/ce via spare args);
//        4 bf16 row-major A.
// EMB: set-0 epilogue adds normalized geometric image embedding (keyval).
template<int BR, int KCH, int NOT, int AMODE, int LNF, int BIASF, int ACT, int SCL,
         int ADDM, int STM, int ASCL, int DUAL, int OUTBF, int QSCL, int WRLN, int EMB>
__global__ __launch_bounds__(256)
void k_gemm_mfma(const float* __restrict__ A, const float* __restrict__ W,
                 const float* __restrict__ bias, const float* __restrict__ addb,
                 const float* __restrict__ ascale, const float* __restrict__ W2,
                 const float* __restrict__ bias2, void* __restrict__ out2v,
                 float* __restrict__ aux, void* __restrict__ outv) {
    constexpr int NI = KCH * 128;
    constexpr int RW = BR / 16;
    constexpr int CT = 8 / (4 / RW);
    __shared__ unsigned short Al[BR * 136];
    __shared__ unsigned short Wl[128 * 136];
    const int t = threadIdx.x;
    const int rb = blockIdx.x * BR;
    const int co = blockIdx.y * 128;
    const int lane = t & 63, wv = t >> 6;
    const int la = lane & 15, g = lane >> 4;
    const int roww = wv % RW, colg = wv / RW;

    if constexpr (KCH == 1) {
        if constexpr (AMODE == 1) {
            int n = rb / PIMG, p0 = rb % PIMG;
            int r = t & 63, kseg = t >> 6;
            #pragma unroll
            for (int j8 = 0; j8 < 4; ++j8) {
                u16x8 o;
                #pragma unroll
                for (int j = 0; j < 8; ++j) {
                    int k = kseg * 32 + j8 * 8 + j;
                    float v = A[((size_t)(n * 128 + k)) * PIMG + p0 + r];
                    o[j] = f2bf(fmaxf(v * BN_S, 0.0f));
                }
                *(u16x8*)&Al[r * 136 + kseg * 32 + j8 * 8] = o;
            }
        } else {
            constexpr int TPR = 256 / BR;
            constexpr int CPT = 128 / TPR;
            int r = t / TPR, seg = t % TPR;
            float v[CPT];
            if constexpr (AMODE == 2) {
                int hw = rb + r;
                int h = hw >> 6, w = hw & 63;
                int l = (h >> 3) * 8 + (w >> 3), ww = (h & 7) * 8 + (w & 7);
                const float* src = A + ((size_t)(l * 64 + ww)) * 6 * 128 + seg * CPT;
                #pragma unroll
                for (int j = 0; j < CPT; ++j) v[j] = 0.f;
                #pragma unroll
                for (int n = 0; n < 6; ++n)
                    #pragma unroll
                    for (int j4 = 0; j4 < CPT / 4; ++j4) {
                        float4 x4 = *(const float4*)&src[n * 128 + 4 * j4];
                        v[4*j4]   += x4.x; v[4*j4+1] += x4.y;
                        v[4*j4+2] += x4.z; v[4*j4+3] += x4.w;
                    }
                #pragma unroll
                for (int j = 0; j < CPT; ++j) v[j] *= (1.0f / 6.0f);
            } else if constexpr (AMODE == 3) {
                // fused query: addb=bev, ascale=x_cl, W2=be_w, bias2=be_b,
                // out2v=E_inv, aux=ce_w
                int grow = rb + r;
                int n = grow >> 12, p = grow & 4095;
                const float* E = ((const float*)out2v) + n * 16;
                const float* cew = (const float*)aux;
                float bp0 = addb[p], bp1 = addb[PBEV + p];
                float ss = 0.f;
                #pragma unroll
                for (int j = 0; j < CPT; ++j) {
                    int c = seg * CPT + j;
                    float cemb = E[3]  * cew[c*4+0] + E[7]  * cew[c*4+1]
                               + E[11] * cew[c*4+2] + E[15] * cew[c*4+3];
                    float emb = bp0 * W2[c*2] + bp1 * W2[c*2+1] + bias2[c] - cemb;
                    v[j] = emb; ss += emb * emb;
                }
                #pragma unroll
                for (int o = 1; o < TPR; o <<= 1) ss += __shfl_xor(ss, o, 64);
                float invn = 1.0f / (sqrtf(ss) + 1e-7f);
                const float* xr = ascale + (size_t)p * 128 + seg * CPT;
                #pragma unroll
                for (int j = 0; j < CPT; ++j) v[j] = v[j] * invn + xr[j];
            } else if constexpr (AMODE == 4) {
                const unsigned short* ab = ((const unsigned short*)A)
                    + (size_t)(rb + r) * 128 + seg * CPT;
                #pragma unroll
                for (int j8 = 0; j8 < CPT / 8; ++j8) {
                    u16x8 raw = *(const u16x8*)&ab[8 * j8];
                    #pragma unroll
                    for (int j = 0; j < 8; ++j) v[8 * j8 + j] = bf2f(raw[j]);
                }
            } else {
                const float* ar = A + (size_t)(rb + r) * 128 + seg * CPT;
                #pragma unroll
                for (int j4 = 0; j4 < CPT / 4; ++j4)
                    *(float4*)&v[4 * j4] = *(const float4*)&ar[4 * j4];
            }
            if constexpr (LNF) {
                float s = 0.f;
                #pragma unroll
                for (int j = 0; j < CPT; ++j) s += v[j];
                #pragma unroll
                for (int o = 1; o < TPR; o <<= 1) s += __shfl_xor(s, o, 64);
                float mu = s * (1.0f / 128.0f);
                float ss = 0.f;
                #pragma unroll
                for (int j = 0; j < CPT; ++j) { float d = v[j] - mu; ss += d * d; }
                #pragma unroll
                for (int o = 1; o < TPR; o <<= 1) ss += __shfl_xor(ss, o, 64);
                float rs = rsqrtf(ss * (1.0f / 128.0f) + LN_EPS);
                #pragma unroll
                for (int j = 0; j < CPT; ++j) v[j] = (v[j] - mu) * rs;
                if constexpr (WRLN) {
                    if (blockIdx.y == 0) {
                        #pragma unroll
                        for (int j4 = 0; j4 < CPT / 4; ++j4) {
                            float4 o4 = {v[4*j4], v[4*j4+1], v[4*j4+2], v[4*j4+3]};
                            *(float4*)&aux[(size_t)(rb + r) * 128 + seg * CPT + 4 * j4] = o4;
                        }
                    }
                }
            }
            #pragma unroll
            for (int j8 = 0; j8 < CPT / 8; ++j8) {
                u16x8 o;
                #pragma unroll
                for (int j = 0; j < 8; ++j) o[j] = f2bf(v[8 * j8 + j]);
                *(u16x8*)&Al[r * 136 + seg * CPT + 8 * j8] = o;
            }
        }
    }

    #pragma unroll 1
    for (int set = 0; set <= DUAL; ++set) {
        const float* Wc = set ? W2 : W;
        const float* bc = set ? bias2 : bias;
        void* ocv = set ? out2v : outv;
        f32x4 acc[CT];
        #pragma unroll
        for (int i = 0; i < CT; ++i) acc[i] = (f32x4){0.f, 0.f, 0.f, 0.f};

        #pragma unroll 1
        for (int kc = 0; kc < KCH; ++kc) {
            if (set || kc) __syncthreads();
            if constexpr (KCH > 1) {
                constexpr int TPR = 256 / BR;
                constexpr int CPT = 128 / TPR;
                int r = t / TPR, seg = t % TPR;
                const float* ar = A + (size_t)(rb + r) * NI + kc * 128 + seg * CPT;
                #pragma unroll
                for (int j8 = 0; j8 < CPT / 8; ++j8) {
                    float4 v0 = *(const float4*)&ar[8 * j8];
                    float4 v1 = *(const float4*)&ar[8 * j8 + 4];
                    if constexpr (ASCL) {
                        const float* sc = ascale + kc * 128 + seg * CPT + 8 * j8;
                        v0.x *= sc[0]; v0.y *= sc[1]; v0.z *= sc[2]; v0.w *= sc[3];
                        v1.x *= sc[4]; v1.y *= sc[5]; v1.z *= sc[6]; v1.w *= sc[7];
                    }
                    u16x8 o = { f2bf(v0.x), f2bf(v0.y), f2bf(v0.z), f2bf(v0.w),
                                f2bf(v1.x), f2bf(v1.y), f2bf(v1.z), f2bf(v1.w) };
                    *(u16x8*)&Al[r * 136 + seg * CPT + 8 * j8] = o;
                }
            }
            #pragma unroll
            for (int i = 0; i < 8; ++i) {
                int chunk = i * 256 + t;
                int c = chunk >> 4, k8 = chunk & 15;
                const float* wr = &Wc[(size_t)(co + c) * NI + kc * 128 + k8 * 8];
                float4 v0 = *(const float4*)&wr[0];
                float4 v1 = *(const float4*)&wr[4];
                u16x8 o = { f2bf(v0.x), f2bf(v0.y), f2bf(v0.z), f2bf(v0.w),
                            f2bf(v1.x), f2bf(v1.y), f2bf(v1.z), f2bf(v1.w) };
                *(u16x8*)&Wl[c * 136 + k8 * 8] = o;
            }
            __syncthreads();
            short8 af[4];
            #pragma unroll
            for (int ks = 0; ks < 4; ++ks)
                af[ks] = *(short8*)&Al[(roww * 16 + la) * 136 + ks * 32 + g * 8];
            #pragma unroll
            for (int cti = 0; cti < CT; ++cti) {
                int ct = colg * CT + cti;
                #pragma unroll
                for (int ks = 0; ks < 4; ++ks) {
                    short8 bf = *(short8*)&Wl[(ct * 16 + la) * 136 + ks * 32 + g * 8];
                    acc[cti] = __builtin_amdgcn_mfma_f32_16x16x32_bf16(af[ks], bf, acc[cti], 0, 0, 0);
                }
            }
        }

        // EMB: normalized geometric image embedding (keyval set 0)
        float embv[CT][4];
        float invr[4];
        if constexpr (EMB) {
            if (set == 0) {
                int n = rb / PIMG;
                const float* Ii = ascale + n * 9;   // I_inv
                const float* E  = addb + n * 16;    // E_inv
                float d0[4], d1[4], d2[4], d3[4];
                #pragma unroll
                for (int r = 0; r < 4; ++r) {
                    int row = rb + roww * 16 + g * 4 + r;
                    int p = row % PIMG;
                    int hh = p / FWW, wp = p % FWW;
                    float gx = (float)wp * (768.0f / 95.0f);
                    float gy = (float)hh * (256.0f / 31.0f);
                    float c0 = Ii[0]*gx + Ii[1]*gy + Ii[2];
                    float c1 = Ii[3]*gx + Ii[4]*gy + Ii[5];
                    float c2 = Ii[6]*gx + Ii[7]*gy + Ii[8];
                    d0[r] = E[0]*c0  + E[1]*c1  + E[2]*c2  + E[3];
                    d1[r] = E[4]*c0  + E[5]*c1  + E[6]*c2  + E[7];
                    d2[r] = E[8]*c0  + E[9]*c1  + E[10]*c2 + E[11];
                    d3[r] = E[12]*c0 + E[13]*c1 + E[14]*c2 + E[15];
                }
                float ssr[4] = {0.f, 0.f, 0.f, 0.f};
                #pragma unroll
                for (int cti = 0; cti < CT; ++cti) {
                    int col = co + (colg * CT + cti) * 16 + la;
                    const float* iw = bias + col * 4;    // ie_w
                    const float* cw = bias2 + col * 4;   // ce_w
                    float cemb = E[3]*cw[0] + E[7]*cw[1] + E[11]*cw[2] + E[15]*cw[3];
                    #pragma unroll
                    for (int r = 0; r < 4; ++r) {
                        float e = d0[r]*iw[0] + d1[r]*iw[1] + d2[r]*iw[2] + d3[r]*iw[3] - cemb;
                        embv[cti][r] = e;
                        ssr[r] += e * e;
                    }
                }
                #pragma unroll
                for (int r = 0; r < 4; ++r) {
                    float s = ssr[r];
                    s += __shfl_xor(s, 1); s += __shfl_xor(s, 2);
                    s += __shfl_xor(s, 4); s += __shfl_xor(s, 8);
                    invr[r] = 1.0f / (sqrtf(s) + 1e-7f);
                }
            }
        }

        #pragma unroll
        for (int cti = 0; cti < CT; ++cti) {
            int ct = colg * CT + cti;
            int col = co + ct * 16 + la;
            float bv = 0.f;
            if constexpr (BIASF) bv = bc[col];
            if constexpr (STM == 1) {
                int row0 = rb + roww * 16 + g * 4;
                float vv[4];
                #pragma unroll
                for (int r = 0; r < 4; ++r) {
                    float v = acc[cti][r] + bv;
                    if constexpr (SCL)  v *= BN_S;
                    if constexpr (ACT)  v = gelu_f(v);
                    if constexpr (QSCL) v *= ATT_SCALE;
                    vv[r] = v;
                }
                float4 o4 = {vv[0], vv[1], vv[2], vv[3]};
                *(float4*)&((float*)ocv)[(size_t)col * PBEV + row0] = o4;
            } else {
                #pragma unroll
                for (int r = 0; r < 4; ++r) {
                    int row = rb + roww * 16 + g * 4 + r;
                    float v = acc[cti][r] + bv;
                    if constexpr (SCL)  v *= BN_S;
                    if constexpr (ACT)  v = gelu_f(v);
                    if constexpr (QSCL) v *= ATT_SCALE;
                    if constexpr (EMB) { if (set == 0) v += embv[cti][r] * invr[r]; }
                    if constexpr (ADDM == 1) { if (set == 0) v += addb[(size_t)row * 128 + col]; }
                    if constexpr (ADDM == 2) { if (set == 0) v += addb[(size_t)col * PBEV + row]; }
                    if constexpr (OUTBF) ((unsigned short*)ocv)[(size_t)row * NOT + col] = f2bf(v);
                    else                 ((float*)ocv)[(size_t)row * NOT + col] = v;
                }
            }
        }
    }
}

// ---------- fused MFMA MLP: out = X + W2.gelu(W1.(LN?)(X) + b1) + b2 ----------
template<int LNF>
__global__ __launch_bounds__(256)
void k_mlp_mfma(const float* __restrict__ X, const float* __restrict__ W1,
                const float* __restrict__ b1, const float* __restrict__ W2,
                const float* __restrict__ b2, float* __restrict__ out) {
    __shared__ unsigned short Al[16 * 136];
    __shared__ unsigned short Wl[128 * 72];
    __shared__ unsigned short Gl[16 * 264];
    const int t = threadIdx.x;
    const int rb = blockIdx.x * 16;
    const int lane = t & 63, wv = t >> 6;
    const int la = lane & 15, g = lane >> 4;

    {
        int r = t >> 4, seg = t & 15;
        const float* ar = X + (size_t)(rb + r) * 128 + seg * 8;
        float v[8];
        *(float4*)&v[0] = *(const float4*)&ar[0];
        *(float4*)&v[4] = *(const float4*)&ar[4];
        if constexpr (LNF) {
            float s = 0.f;
            #pragma unroll
            for (int j = 0; j < 8; ++j) s += v[j];
            s += __shfl_xor(s, 1); s += __shfl_xor(s, 2);
            s += __shfl_xor(s, 4); s += __shfl_xor(s, 8);
            float mu = s * (1.0f / 128.0f);
            float ss = 0.f;
            #pragma unroll
            for (int j = 0; j < 8; ++j) { float d = v[j] - mu; ss += d * d; }
            ss += __shfl_xor(ss, 1); ss += __shfl_xor(ss, 2);
            ss += __shfl_xor(ss, 4); ss += __shfl_xor(ss, 8);
            float rs = rsqrtf(ss * (1.0f / 128.0f) + LN_EPS);
            #pragma unroll
            for (int j = 0; j < 8; ++j) v[j] = (v[j] - mu) * rs;
        }
        u16x8 o;
        #pragma unroll
        for (int j = 0; j < 8; ++j) o[j] = f2bf(v[j]);
        *(u16x8*)&Al[r * 136 + seg * 8] = o;
    }
    __syncthreads();

    short8 af[4];
    #pragma unroll
    for (int ks = 0; ks < 4; ++ks)
        af[ks] = *(short8*)&Al[la * 136 + ks * 32 + g * 8];

    #pragma unroll 1
    for (int cc = 0; cc < 4; ++cc) {
        {
            int c = t >> 2, s2 = t & 3;
            const float* wr = W1 + (size_t)(cc * 64 + c) * 128 + s2 * 32;
            #pragma unroll
            for (int j8 = 0; j8 < 4; ++j8) {
                float4 v0 = *(const float4*)&wr[8 * j8];
                float4 v1 = *(const float4*)&wr[8 * j8 + 4];
                u16x8 o = { f2bf(v0.x), f2bf(v0.y), f2bf(v0.z), f2bf(v0.w),
                            f2bf(v1.x), f2bf(v1.y), f2bf(v1.z), f2bf(v1.w) };
                *(u16x8*)&Wl[c * 136 + s2 * 32 + 8 * j8] = o;
            }
        }
        __syncthreads();
        f32x4 acc = (f32x4){0.f, 0.f, 0.f, 0.f};
        #pragma unroll
        for (int ks = 0; ks < 4; ++ks) {
            short8 bf = *(short8*)&Wl[(wv * 16 + la) * 136 + ks * 32 + g * 8];
            acc = __builtin_amdgcn_mfma_f32_16x16x32_bf16(af[ks], bf, acc, 0, 0, 0);
        }
        int col = cc * 64 + wv * 16 + la;
        float bv = b1[col];
        #pragma unroll
        for (int r = 0; r < 4; ++r)
            Gl[(g * 4 + r) * 264 + col] = f2bf(gelu_f(acc[r] + bv));
        __syncthreads();
    }

    f32x4 acc2[2];
    acc2[0] = (f32x4){0.f, 0.f, 0.f, 0.f};
    acc2[1] = (f32x4){0.f, 0.f, 0.f, 0.f};
    #pragma unroll 1
    for (int kc = 0; kc < 4; ++kc) {
        {
            int c = t >> 1, s2 = t & 1;
            const float* wr = W2 + (size_t)c * 256 + kc * 64 + s2 * 32;
            #pragma unroll
            for (int j8 = 0; j8 < 4; ++j8) {
                float4 v0 = *(const float4*)&wr[8 * j8];
                float4 v1 = *(const float4*)&wr[8 * j8 + 4];
                u16x8 o = { f2bf(v0.x), f2bf(v0.y), f2bf(v0.z), f2bf(v0.w),
                            f2bf(v1.x), f2bf(v1.y), f2bf(v1.z), f2bf(v1.w) };
                *(u16x8*)&Wl[c * 72 + s2 * 32 + 8 * j8] = o;
            }
        }
        __syncthreads();
        #pragma unroll
        for (int half = 0; half < 2; ++half) {
            short8 pf = *(short8*)&Gl[la * 264 + kc * 64 + half * 32 + g * 8];
            #pragma unroll
            for (int ct = 0; ct < 2; ++ct) {
                short8 bf = *(short8*)&Wl[((wv * 2 + ct) * 16 + la) * 72 + half * 32 + g * 8];
                acc2[ct] = __builtin_amdgcn_mfma_f32_16x16x32_bf16(pf, bf, acc2[ct], 0, 0, 0);
            }
        }
        __syncthreads();
    }
    #pragma unroll
    for (int ct = 0; ct < 2; ++ct) {
        int col = (wv * 2 + ct) * 16 + la;
        float bv = b2[col];
        #pragma unroll
        for (int r = 0; r < 4; ++r) {
            int row = rb + g * 4 + r;
            out[(size_t)row * 128 + col] = acc2[ct][r] + bv + X[(size_t)row * 128 + col];
        }
    }
}

// ---------- MFMA flash attention: S^T trick, in-register P re-layout via shfl ----------
template<int MODE>
__global__ __launch_bounds__(MODE == 1 ? 512 : 256)
void k_attn_mfma(const unsigned short* __restrict__ qh, const unsigned short* __restrict__ kh,
                 const unsigned short* __restrict__ vh, float* __restrict__ aout) {
    constexpr int WAVES = (MODE == 1) ? 8 : 4;
    constexpr int QTPW  = (MODE == 1) ? 3 : 1;
    constexpr int T = WAVES * 64;
    const int l = blockIdx.x, m = blockIdx.y;
    const int xw = l >> 3, yw = l & 7;
    const int t = threadIdx.x;
    const int lane = t & 63, wv = t >> 6;
    const int la = lane & 15, g = lane >> 4;

    __shared__ unsigned short Kl[KROWS * 40];
    __shared__ unsigned short Vt[32 * 312];

    for (int i = t; i < KROWS * 4; i += T) {
        int row = i >> 2, seg = i & 3;
        int n = row / 48, kk = row % 48;
        int k1 = kk / 12, k2 = kk % 12;
        int h, w;
        if (MODE == 1) { h = xw * 4 + k1;  w = yw * 12 + k2; }
        else           { h = k1 * 8 + xw;  w = k2 * 8 + yw;  }
        size_t src = ((size_t)(n * PIMG + h * FWW + w)) * 128 + m * DHD + seg * 8;
        short8 kv = *(const short8*)&kh[src];
        *(short8*)&Kl[row * 40 + seg * 8] = kv;
        short8 vv = *(const short8*)&vh[src];
        #pragma unroll
        for (int j = 0; j < 8; ++j)
            Vt[(seg * 8 + j) * 312 + row] = (unsigned short)vv[j];
    }

    short8 qf[QTPW];
    #pragma unroll
    for (int qt = 0; qt < QTPW; ++qt) {
        int q = (wv * QTPW + qt) * 16 + la;
        int row;
        if (MODE == 1) {
            int n = q >> 6, ww = q & 63;
            row = n * PBEV + (xw * 8 + (ww >> 3)) * 64 + yw * 8 + (ww & 7);
        } else {
            row = ((q >> 3) * 8 + xw) * 64 + (q & 7) * 8 + yw;
        }
        qf[qt] = *(const short8*)&qh[(size_t)row * 128 + m * DHD + g * 8];
    }
    __syncthreads();

    f32x4 acc[QTPW][2];
    float srow[QTPW];
    #pragma unroll
    for (int qt = 0; qt < QTPW; ++qt) {
        acc[qt][0] = (f32x4){0.f, 0.f, 0.f, 0.f};
        acc[qt][1] = (f32x4){0.f, 0.f, 0.f, 0.f};
        srow[qt] = 0.f;
    }
    const int a0 = la + 32 * (g & 1);
    const int a1 = a0 + 16;
    const bool selA = (g < 2);

    #pragma unroll 1
    for (int c = 0; c < 9; ++c) {
        const int kk0 = c * 32;
        short8 kf0 = *(short8*)&Kl[(kk0 + la) * 40 + g * 8];
        short8 kf1 = *(short8*)&Kl[(kk0 + 16 + la) * 40 + g * 8];
        short8 vf0 = *(short8*)&Vt[la * 312 + kk0 + g * 8];
        short8 vf1 = *(short8*)&Vt[(16 + la) * 312 + kk0 + g * 8];
        #pragma unroll
        for (int qt = 0; qt < QTPW; ++qt) {
            // S^T = K . Q^T : thread holds S^T[key = g*4+r (+16)][q = la]
            f32x4 sA = __builtin_amdgcn_mfma_f32_16x16x32_bf16(kf0, qf[qt], (f32x4){0.f,0.f,0.f,0.f}, 0, 0, 0);
            f32x4 sB = __builtin_amdgcn_mfma_f32_16x16x32_bf16(kf1, qf[qt], (f32x4){0.f,0.f,0.f,0.f}, 0, 0, 0);
            float pA[4], pB[4];
            #pragma unroll
            for (int r = 0; r < 4; ++r) { pA[r] = __expf(sA[r]); pB[r] = __expf(sB[r]); }
            srow[qt] += ((pA[0] + pA[1]) + (pA[2] + pA[3]))
                      + ((pB[0] + pB[1]) + (pB[2] + pB[3]));
            unsigned int loA = (unsigned int)f2bf(pA[0]) | ((unsigned int)f2bf(pA[1]) << 16);
            unsigned int hiA = (unsigned int)f2bf(pA[2]) | ((unsigned int)f2bf(pA[3]) << 16);
            unsigned int loB = (unsigned int)f2bf(pB[0]) | ((unsigned int)f2bf(pB[1]) << 16);
            unsigned int hiB = (unsigned int)f2bf(pB[2]) | ((unsigned int)f2bf(pB[3]) << 16);
            // P A-frag: thread (la,g) needs P[q=la][keys g*8..g*8+7] = quads 2g, 2g+1
            int w0A = __shfl((int)loA, a0); int w0B = __shfl((int)loB, a0);
            int w1A = __shfl((int)hiA, a0); int w1B = __shfl((int)hiB, a0);
            int w2A = __shfl((int)loA, a1); int w2B = __shfl((int)loB, a1);
            int w3A = __shfl((int)hiA, a1); int w3B = __shfl((int)hiB, a1);
            union { int u[4]; short8 s; } pu;
            pu.u[0] = selA ? w0A : w0B;
            pu.u[1] = selA ? w1A : w1B;
            pu.u[2] = selA ? w2A : w2B;
            pu.u[3] = selA ? w3A : w3B;
            acc[qt][0] = __builtin_amdgcn_mfma_f32_16x16x32_bf16(pu.s, vf0, acc[qt][0], 0, 0, 0);
            acc[qt][1] = __builtin_amdgcn_mfma_f32_16x16x32_bf16(pu.s, vf1, acc[qt][1], 0, 0, 0);
        }
    }

    #pragma unroll
    for (int qt = 0; qt < QTPW; ++qt) {
        float s = srow[qt];
        s += __shfl_xor(s, 16);
        s += __shfl_xor(s, 32);
        #pragma unroll
        for (int r = 0; r < 4; ++r) {
            float sq = __shfl(s, g * 4 + r);
            float inv = 1.0f / sq;
            int q = (wv * QTPW + qt) * 16 + g * 4 + r;
            size_t orow;
            if (MODE == 1) {
                int n = q >> 6, ww = q & 63;
                orow = (size_t)(l * 64 + ww) * 6 + n;
            } else {
                orow = (size_t)(((q >> 3) * 8 + xw) * 64 + (q & 7) * 8 + yw);
            }
            float* ap = aout + orow * 128 + m * DHD;
            ap[la]      = acc[qt][0][r] * inv;
            ap[16 + la] = acc[qt][1][r] * inv;
        }
    }
}

// ---------- depthwise 3x3 + gelu + SE partials ----------
__global__ void k_dwconv(const float* __restrict__ ex, const float* __restrict__ dwgt,
                         float* __restrict__ dwout, float* __restrict__ separt) {
    const int TILE = 16;
    int ch = threadIdx.x;
    int hw0 = blockIdx.x * TILE;
    float wreg[9];
    #pragma unroll
    for (int i = 0; i < 9; ++i) wreg[i] = dwgt[ch * 9 + i];
    float sacc = 0.f;
    for (int ti = 0; ti < TILE; ++ti) {
        int hw = hw0 + ti;
        int h = hw >> 6, w = hw & 63;
        float s = 0.f;
        #pragma unroll
        for (int dy = -1; dy <= 1; ++dy) {
            int h2 = h + dy;
            if (h2 < 0 || h2 >= 64) continue;
            #pragma unroll
            for (int dx = -1; dx <= 1; ++dx) {
                int w2 = w + dx;
                if (w2 < 0 || w2 >= 64) continue;
                s += ex[((size_t)(h2 * 64 + w2)) * 512 + ch] * wreg[(dy + 1) * 3 + (dx + 1)];
            }
        }
        float o = gelu_f(s * BN_S);
        dwout[(size_t)hw * 512 + ch] = o;
        sacc += o;
    }
    separt[(size_t)blockIdx.x * 512 + ch] = sacc;
}

// ---------- SE reduce stage 1 ----------
__global__ void k_sered(const float* __restrict__ separt, float* __restrict__ separt2) {
    int t = threadIdx.x, bb = blockIdx.x;
    float s = 0.f;
    #pragma unroll
    for (int i = 0; i < 16; ++i)
        s += separt[(size_t)(bb * 16 + i) * 512 + t];
    separt2[(size_t)bb * 512 + t] = s;
}

// ---------- SE final ----------
__global__ void k_se(const float* __restrict__ separt2,
                     const float* __restrict__ s1w, const float* __restrict__ s1b,
                     const float* __restrict__ s2w, const float* __restrict__ s2b,
                     float* __restrict__ se) {
    __shared__ float mean[512];
    __shared__ float s1[32];
    int t = threadIdx.x;
    float s = 0.f;
    #pragma unroll
    for (int b = 0; b < 16; ++b) s += separt2[b * 512 + t];
    mean[t] = s * (1.0f / 4096.0f);
    __syncthreads();
    int u = t >> 4, seg = t & 15;
    float acc = 0.f;
    #pragma unroll
    for (int j = 0; j < 32; ++j) {
        int c = seg + 16 * j;
        acc += mean[c] * s1w[u * 512 + c];
    }
    acc += __shfl_xor(acc, 1); acc += __shfl_xor(acc, 2);
    acc += __shfl_xor(acc, 4); acc += __shfl_xor(acc, 8);
    if (seg == 0) s1[u] = gelu_f(acc + s1b[u]);
    __syncthreads();
    float a2 = s2b[t];
    #pragma unroll
    for (int j = 0; j < 32; ++j) a2 += s1[j] * s2w[t * 32 + j];
    se[t] = 1.0f / (1.0f + __expf(-a2));
}

extern "C" void kernel_launch(void* const* d_in, const int* in_sizes, int n_in,
                              void* d_out, int out_size, void* d_ws, size_t ws_size,
                              hipStream_t stream) {
    (void)in_sizes; (void)n_in; (void)out_size; (void)ws_size;
    const float* x      = (const float*)d_in[1];
    const float* feat   = (const float*)d_in[2];
    const float* I_inv  = (const float*)d_in[3];
    const float* E_inv  = (const float*)d_in[4];
    const float* bev    = (const float*)d_in[5];
    const float* fl_w   = (const float*)d_in[6];
    const float* fp_w   = (const float*)d_in[7];
    const float* be_w   = (const float*)d_in[8];
    const float* be_b   = (const float*)d_in[9];
    const float* ie_w   = (const float*)d_in[10];
    const float* ce_w   = (const float*)d_in[11];
    const float* a1_qw  = (const float*)d_in[12];
    const float* a1_qb  = (const float*)d_in[13];
    const float* a1_kw  = (const float*)d_in[14];
    const float* a1_kb  = (const float*)d_in[15];
    const float* a1_vw  = (const float*)d_in[16];
    const float* a1_vb  = (const float*)d_in[17];
    const float* a1_pw  = (const float*)d_in[18];
    const float* a1_pb  = (const float*)d_in[19];
    const float* a2_qw  = (const float*)d_in[20];
    const float* a2_qb  = (const float*)d_in[21];
    const float* a2_kw  = (const float*)d_in[22];
    const float* a2_kb  = (const float*)d_in[23];
    const float* a2_vw  = (const float*)d_in[24];
    const float* a2_vb  = (const float*)d_in[25];
    const float* a2_pw  = (const float*)d_in[26];
    const float* a2_pb  = (const float*)d_in[27];
    const float* m1_w1  = (const float*)d_in[28];
    const float* m1_b1  = (const float*)d_in[29];
    const float* m1_w2  = (const float*)d_in[30];
    const float* m1_b2  = (const float*)d_in[31];
    const float* m2_w1  = (const float*)d_in[32];
    const float* m2_b1  = (const float*)d_in[33];
    const float* m2_w2  = (const float*)d_in[34];
    const float* m2_b2  = (const float*)d_in[35];
    const float* mb_ew  = (const float*)d_in[36];
    const float* mb_dw  = (const float*)d_in[37];
    const float* mb_s1w = (const float*)d_in[38];
    const float* mb_s1b = (const float*)d_in[39];
    const float* mb_s2w = (const float*)d_in[40];
    const float* mb_s2b = (const float*)d_in[41];
    const float* mb_pw  = (const float*)d_in[42];
    const float* pm_w1  = (const float*)d_in[43];
    const float* pm_b1  = (const float*)d_in[44];
    const float* pm_w2  = (const float*)d_in[45];
    const float* pm_b2  = (const float*)d_in[46];
    const float* po_w   = (const float*)d_in[47];
    const float* po_b   = (const float*)d_in[48];

    float* ws = (float*)d_ws;
    // de-aliased arena (floats)
    float* x_cl   = ws + 0;          // 524288
    unsigned short* key_b = (unsigned short*)(ws + 524288);    // 1179648 f
    unsigned short* val_b = (unsigned short*)(ws + 1703936);   // 1179648 f
    unsigned short* qh1b  = (unsigned short*)(ws + 2883584);   // 1572864 f
    unsigned short* kh1b  = (unsigned short*)(ws + 4456448);   // 1179648 f
    unsigned short* vh1b  = (unsigned short*)(ws + 5636096);
    unsigned short* kh2b  = (unsigned short*)(ws + 6815744);
    unsigned short* vh2b  = (unsigned short*)(ws + 7995392);
    float* abuf   = ws + 9175040;    // 3145728
    float* qimg   = ws + 12320768;   // 524288
    float* qimg2  = ws + 12845056;
    float* zln    = ws + 13369344;
    float* abuf2  = ws + 13893632;
    float* mbout  = ws + 14417920;
    float* expandb = ws + 14942208;  // 2097152
    float* dwout   = ws + 17039360;  // 2097152
    float* separt  = ws + 19136512;  // 131072
    float* separt2 = ws + 19267584;  // 8192
    float* sebuf   = ws + 19275776;  // 512
    unsigned short* qh2b = qh1b;     // qh1b dead after attn1

    // stage 0: x transpose; key/val (feature transpose + img-embed fused)
    k_transx<<<dim3(128, 4), 256, 0, stream>>>(x, x_cl);
    k_gemm_mfma<64,1,128, 1,0,0,0,0, 0,0,0,1, 1,0,0,1><<<288, 256, 0, stream>>>(
        feat, fp_w, ie_w, E_inv, I_inv, fl_w, ce_w, val_b, nullptr, key_b);

    // stage 1: q/k/v heads (query gen fused into q staging; q pre-scaled)
    k_gemm_mfma<64,1,128, 3,1,1,0,0, 0,0,0,0, 1,1,0,0><<<384, 256, 0, stream>>>(
        nullptr, a1_qw, a1_qb, bev, x_cl, be_w, be_b, (void*)E_inv,
        (float*)ce_w, qh1b);
    k_gemm_mfma<64,1,128, 4,1,1,0,0, 0,0,0,1, 1,0,0,0><<<288, 256, 0, stream>>>(
        (const float*)key_b, a1_kw, a1_kb, nullptr, nullptr, a2_kw, a2_kb,
        kh2b, nullptr, kh1b);
    k_gemm_mfma<64,1,128, 4,1,1,0,0, 0,0,0,1, 1,0,0,0><<<288, 256, 0, stream>>>(
        (const float*)val_b, a1_vw, a1_vb, nullptr, nullptr, a2_vw, a2_vb,
        vh2b, nullptr, vh1b);
    k_attn_mfma<1><<<dim3(64, HEADS), 512, 0, stream>>>(qh1b, kh1b, vh1b, abuf);
    k_gemm_mfma<16,1,128, 2,0,1,0,0, 1,0,0,0, 0,0,0,0><<<256, 256, 0, stream>>>(
        abuf, a1_pw, a1_pb, x_cl, nullptr, nullptr, nullptr, nullptr, nullptr, qimg);
    k_mlp_mfma<1><<<256, 256, 0, stream>>>(qimg, m1_w1, m1_b1, m1_w2, m1_b2, qimg);

    // stage 2: attn2 + MLP2
    k_gemm_mfma<16,1,128, 0,1,1,0,0, 0,0,0,0, 1,1,0,0><<<256, 256, 0, stream>>>(
        qimg, a2_qw, a2_qb, nullptr, nullptr, nullptr, nullptr, nullptr, nullptr, qh2b);
    k_attn_mfma<2><<<dim3(64, HEADS), 256, 0, stream>>>(qh2b, kh2b, vh2b, abuf2);
    k_gemm_mfma<16,1,128, 0,0,1,0,0, 1,0,0,0, 0,0,0,0><<<256, 256, 0, stream>>>(
        abuf2, a2_pw, a2_pb, qimg, nullptr, nullptr, nullptr, nullptr, nullptr, qimg2);
    k_mlp_mfma<1><<<256, 256, 0, stream>>>(qimg2, m2_w1, m2_b1, m2_w2, m2_b2, qimg2);

    // stage 3: postnorm LN fused into expand; MBConv; FFN; proj_out
    k_gemm_mfma<16,1,512, 0,1,0,1,1, 0,0,0,0, 0,0,1,0><<<dim3(256, 4), 256, 0, stream>>>(
        qimg2, mb_ew, nullptr, nullptr, nullptr, nullptr, nullptr, nullptr, zln, expandb);
    k_dwconv<<<256, 512, 0, stream>>>(expandb, mb_dw, dwout, separt);
    k_sered<<<16, 512, 0, stream>>>(separt, separt2);
    k_se<<<1, 512, 0, stream>>>(separt2, mb_s1w, mb_s1b, mb_s2w, mb_s2b, sebuf);
    k_gemm_mfma<16,4,128, 0,0,0,0,1, 1,0,1,0, 0,0,0,0><<<256, 256, 0, stream>>>(
        dwout, mb_pw, nullptr, zln, sebuf, nullptr, nullptr, nullptr, nullptr, mbout);
    k_mlp_mfma<0><<<256, 256, 0, stream>>>(mbout, pm_w1, pm_b1, pm_w2, pm_b2, mbout);
    k_gemm_mfma<16,1,128, 0,0,1,1,0, 0,1,0,0, 0,0,0,0><<<256, 256, 0, stream>>>(
        mbout, po_w, po_b, nullptr, nullptr, nullptr, nullptr, nullptr, nullptr, (float*)d_out);
}

// Round 11
// 155.206 us; speedup vs baseline: 1.7729x; 1.2731x over previous
//
#include <hip/hip_runtime.h>
#include <math.h>

#define NV 6
#define FHH 32
#define FWW 96
#define PIMG (FHH*FWW)   // 3072
#define HH 64
#define WWD 64
#define PBEV (HH*WWD)    // 4096
#define HEADS 4
#define DHD 32
#define KROWS 288
#define BN_S 0.9999950000374996f
#define LN_EPS 1e-5f
#define ATT_SCALE 0.17677669529663687f  // 32^-0.5

typedef __attribute__((ext_vector_type(8))) short short8;
typedef __attribute__((ext_vector_type(4))) float f32x4;
typedef __attribute__((ext_vector_type(8))) unsigned short u16x8;

__device__ __forceinline__ float gelu_f(float x) {
    return 0.5f * x * (1.0f + erff(x * 0.70710678118654752f));
}

__device__ __forceinline__ unsigned short f2bf(float f) {
    union { float f; unsigned int u; } c; c.f = f;
    unsigned int r = (c.u + 0x7fffu + ((c.u >> 16) & 1u)) >> 16;
    return (unsigned short)r;
}

__device__ __forceinline__ float bf2f(unsigned short u) {
    union { unsigned int u; float f; } c; c.u = ((unsigned int)u) << 16;
    return c.f;
}

// bf16 weight arena offsets (u16 elements)
#define OFF_FP    0
#define OFF_FL    16384
#define OFF_A1QW  32768
#define OFF_A1KW  49152
#define OFF_A2KW  65536
#define OFF_A1VW  81920
#define OFF_A2VW  98304
#define OFF_A1PW  114688
#define OFF_M1W1  131072
#define OFF_M1W2  163840
#define OFF_A2QW  196608
#define OFF_A2PW  212992
#define OFF_M2W1  229376
#define OFF_M2W2  262144
#define OFF_MBEW  294912
#define OFF_MBPW  360448
#define OFF_PMW1  425984
#define OFF_PMW2  458752
#define OFF_POW   491520
#define WTOTAL    507904

// ---------- weight f32 -> bf16 arena ----------
__global__ void k_cvtw(const float* p0, const float* p1, const float* p2,
                       const float* p3, const float* p4, const float* p5,
                       const float* p6, const float* p7, const float* p8,
                       const float* p9, const float* p10, const float* p11,
                       const float* p12, const float* p13, const float* p14,
                       const float* p15, const float* p16, const float* p17,
                       const float* p18, unsigned short* wb) {
    int idx = (blockIdx.x * 256 + threadIdx.x) * 8;
    if (idx >= WTOTAL) return;
    const float* s;
    if      (idx < OFF_FL)   s = p0  + idx;
    else if (idx < OFF_A1QW) s = p1  + (idx - OFF_FL);
    else if (idx < OFF_A1KW) s = p2  + (idx - OFF_A1QW);
    else if (idx < OFF_A2KW) s = p3  + (idx - OFF_A1KW);
    else if (idx < OFF_A1VW) s = p4  + (idx - OFF_A2KW);
    else if (idx < OFF_A2VW) s = p5  + (idx - OFF_A1VW);
    else if (idx < OFF_A1PW) s = p6  + (idx - OFF_A2VW);
    else if (idx < OFF_M1W1) s = p7  + (idx - OFF_A1PW);
    else if (idx < OFF_M1W2) s = p8  + (idx - OFF_M1W1);
    else if (idx < OFF_A2QW) s = p9  + (idx - OFF_M1W2);
    else if (idx < OFF_A2PW) s = p10 + (idx - OFF_A2QW);
    else if (idx < OFF_M2W1) s = p11 + (idx - OFF_A2PW);
    else if (idx < OFF_M2W2) s = p12 + (idx - OFF_M2W1);
    else if (idx < OFF_MBEW) s = p13 + (idx - OFF_M2W2);
    else if (idx < OFF_MBPW) s = p14 + (idx - OFF_MBEW);
    else if (idx < OFF_PMW1) s = p15 + (idx - OFF_MBPW);
    else if (idx < OFF_PMW2) s = p16 + (idx - OFF_PMW1);
    else if (idx < OFF_POW)  s = p17 + (idx - OFF_PMW2);
    else                     s = p18 + (idx - OFF_POW);
    float4 v0 = *(const float4*)&s[0];
    float4 v1 = *(const float4*)&s[4];
    u16x8 o = { f2bf(v0.x), f2bf(v0.y), f2bf(v0.z), f2bf(v0.w),
                f2bf(v1.x), f2bf(v1.y), f2bf(v1.z), f2bf(v1.w) };
    *(u16x8*)&wb[idx] = o;
}

// ---------- x transpose: [128][4096] -> [4096][128] ----------
__global__ void k_transx(const float* __restrict__ x, float* __restrict__ x_cl) {
    __shared__ float tile[32][33];
    int c0 = blockIdx.y * 32, p0 = blockIdx.x * 32;
    int tp = threadIdx.x & 31, tg = threadIdx.x >> 5;
    #pragma unroll
    for (int i = 0; i < 4; ++i)
        tile[tg + 8 * i][tp] = x[(size_t)(c0 + tg + 8 * i) * PBEV + p0 + tp];
    __syncthreads();
    #pragma unroll
    for (int i = 0; i < 4; ++i)
        x_cl[(size_t)(p0 + tg + 8 * i) * 128 + c0 + tp] = tile[tp][tg + 8 * i];
}

// ---------- universal MFMA GEMM ----------
template<int BR, int KCH, int NOT, int AMODE, int LNF, int BIASF, int ACT, int SCL,
         int ADDM, int STM, int ASCL, int DUAL, int OUTBF, int QSCL, int WRLN,
         int EMB, int WBF>
__global__ __launch_bounds__(256)
void k_gemm_mfma(const float* __restrict__ A, const float* __restrict__ W,
                 const float* __restrict__ bias, const float* __restrict__ addb,
                 const float* __restrict__ ascale, const float* __restrict__ W2,
                 const float* __restrict__ bias2, void* __restrict__ out2v,
                 float* __restrict__ aux, void* __restrict__ outv) {
    constexpr int NI = KCH * 128;
    constexpr int RW = BR / 16;
    constexpr int CT = 8 / (4 / RW);
    __shared__ unsigned short Al[BR * 136];
    __shared__ unsigned short Wl[128 * 136];
    const int t = threadIdx.x;
    const int rb = blockIdx.x * BR;
    const int co = blockIdx.y * 128;
    const int lane = t & 63, wv = t >> 6;
    const int la = lane & 15, g = lane >> 4;
    const int roww = wv % RW, colg = wv / RW;

    if constexpr (KCH == 1) {
        if constexpr (AMODE == 1) {
            int n = rb / PIMG, p0 = rb % PIMG;
            int r = t & 63, kseg = t >> 6;
            #pragma unroll
            for (int j8 = 0; j8 < 4; ++j8) {
                u16x8 o;
                #pragma unroll
                for (int j = 0; j < 8; ++j) {
                    int k = kseg * 32 + j8 * 8 + j;
                    float v = A[((size_t)(n * 128 + k)) * PIMG + p0 + r];
                    o[j] = f2bf(fmaxf(v * BN_S, 0.0f));
                }
                *(u16x8*)&Al[r * 136 + kseg * 32 + j8 * 8] = o;
            }
        } else {
            constexpr int TPR = 256 / BR;
            constexpr int CPT = 128 / TPR;
            int r = t / TPR, seg = t % TPR;
            float v[CPT];
            if constexpr (AMODE == 3) {
                // fused query: addb=bev, ascale=x_cl, W2=be_w, bias2=be_b,
                // out2v=E_inv, aux=ce_w
                int grow = rb + r;
                int n = grow >> 12, p = grow & 4095;
                const float* E = ((const float*)out2v) + n * 16;
                const float* cew = (const float*)aux;
                float bp0 = addb[p], bp1 = addb[PBEV + p];
                float ss = 0.f;
                #pragma unroll
                for (int j = 0; j < CPT; ++j) {
                    int c = seg * CPT + j;
                    float cemb = E[3]  * cew[c*4+0] + E[7]  * cew[c*4+1]
                               + E[11] * cew[c*4+2] + E[15] * cew[c*4+3];
                    float emb = bp0 * W2[c*2] + bp1 * W2[c*2+1] + bias2[c] - cemb;
                    v[j] = emb; ss += emb * emb;
                }
                #pragma unroll
                for (int o = 1; o < TPR; o <<= 1) ss += __shfl_xor(ss, o, 64);
                float invn = 1.0f / (sqrtf(ss) + 1e-7f);
                const float* xr = ascale + (size_t)p * 128 + seg * CPT;
                #pragma unroll
                for (int j = 0; j < CPT; ++j) v[j] = v[j] * invn + xr[j];
            } else if constexpr (AMODE == 4) {
                const unsigned short* ab = ((const unsigned short*)A)
                    + (size_t)(rb + r) * 128 + seg * CPT;
                #pragma unroll
                for (int j8 = 0; j8 < CPT / 8; ++j8) {
                    u16x8 raw = *(const u16x8*)&ab[8 * j8];
                    #pragma unroll
                    for (int j = 0; j < 8; ++j) v[8 * j8 + j] = bf2f(raw[j]);
                }
            } else {
                const float* ar = A + (size_t)(rb + r) * 128 + seg * CPT;
                #pragma unroll
                for (int j4 = 0; j4 < CPT / 4; ++j4)
                    *(float4*)&v[4 * j4] = *(const float4*)&ar[4 * j4];
            }
            if constexpr (LNF) {
                float s = 0.f;
                #pragma unroll
                for (int j = 0; j < CPT; ++j) s += v[j];
                #pragma unroll
                for (int o = 1; o < TPR; o <<= 1) s += __shfl_xor(s, o, 64);
                float mu = s * (1.0f / 128.0f);
                float ss = 0.f;
                #pragma unroll
                for (int j = 0; j < CPT; ++j) { float d = v[j] - mu; ss += d * d; }
                #pragma unroll
                for (int o = 1; o < TPR; o <<= 1) ss += __shfl_xor(ss, o, 64);
                float rs = rsqrtf(ss * (1.0f / 128.0f) + LN_EPS);
                #pragma unroll
                for (int j = 0; j < CPT; ++j) v[j] = (v[j] - mu) * rs;
                if constexpr (WRLN) {
                    if (blockIdx.y == 0) {
                        #pragma unroll
                        for (int j4 = 0; j4 < CPT / 4; ++j4) {
                            float4 o4 = {v[4*j4], v[4*j4+1], v[4*j4+2], v[4*j4+3]};
                            *(float4*)&aux[(size_t)(rb + r) * 128 + seg * CPT + 4 * j4] = o4;
                        }
                    }
                }
            }
            #pragma unroll
            for (int j8 = 0; j8 < CPT / 8; ++j8) {
                u16x8 o;
                #pragma unroll
                for (int j = 0; j < 8; ++j) o[j] = f2bf(v[8 * j8 + j]);
                *(u16x8*)&Al[r * 136 + seg * CPT + 8 * j8] = o;
            }
        }
    }

    #pragma unroll 1
    for (int set = 0; set <= DUAL; ++set) {
        const float* Wc = set ? W2 : W;
        const float* bc = set ? bias2 : bias;
        void* ocv = set ? out2v : outv;
        f32x4 acc[CT];
        #pragma unroll
        for (int i = 0; i < CT; ++i) acc[i] = (f32x4){0.f, 0.f, 0.f, 0.f};

        #pragma unroll 1
        for (int kc = 0; kc < KCH; ++kc) {
            if (set || kc) __syncthreads();
            #pragma unroll
            for (int i = 0; i < 8; ++i) {
                int chunk = i * 256 + t;
                int c = chunk >> 4, k8 = chunk & 15;
                if constexpr (WBF) {
                    const unsigned short* wr = ((const unsigned short*)Wc)
                        + (size_t)(co + c) * NI + kc * 128 + k8 * 8;
                    *(u16x8*)&Wl[c * 136 + k8 * 8] = *(const u16x8*)wr;
                } else {
                    const float* wr = &Wc[(size_t)(co + c) * NI + kc * 128 + k8 * 8];
                    float4 v0 = *(const float4*)&wr[0];
                    float4 v1 = *(const float4*)&wr[4];
                    u16x8 o = { f2bf(v0.x), f2bf(v0.y), f2bf(v0.z), f2bf(v0.w),
                                f2bf(v1.x), f2bf(v1.y), f2bf(v1.z), f2bf(v1.w) };
                    *(u16x8*)&Wl[c * 136 + k8 * 8] = o;
                }
            }
            __syncthreads();
            short8 af[4];
            #pragma unroll
            for (int ks = 0; ks < 4; ++ks)
                af[ks] = *(short8*)&Al[(roww * 16 + la) * 136 + ks * 32 + g * 8];
            #pragma unroll
            for (int cti = 0; cti < CT; ++cti) {
                int ct = colg * CT + cti;
                #pragma unroll
                for (int ks = 0; ks < 4; ++ks) {
                    short8 bf = *(short8*)&Wl[(ct * 16 + la) * 136 + ks * 32 + g * 8];
                    acc[cti] = __builtin_amdgcn_mfma_f32_16x16x32_bf16(af[ks], bf, acc[cti], 0, 0, 0);
                }
            }
        }

        float embv[CT][4];
        float invr[4];
        if constexpr (EMB) {
            if (set == 0) {
                int n = rb / PIMG;
                const float* Ii = ascale + n * 9;
                const float* E  = addb + n * 16;
                float d0[4], d1[4], d2[4], d3[4];
                #pragma unroll
                for (int r = 0; r < 4; ++r) {
                    int row = rb + roww * 16 + g * 4 + r;
                    int p = row % PIMG;
                    int hh = p / FWW, wp = p % FWW;
                    float gx = (float)wp * (768.0f / 95.0f);
                    float gy = (float)hh * (256.0f / 31.0f);
                    float c0 = Ii[0]*gx + Ii[1]*gy + Ii[2];
                    float c1 = Ii[3]*gx + Ii[4]*gy + Ii[5];
                    float c2 = Ii[6]*gx + Ii[7]*gy + Ii[8];
                    d0[r] = E[0]*c0  + E[1]*c1  + E[2]*c2  + E[3];
                    d1[r] = E[4]*c0  + E[5]*c1  + E[6]*c2  + E[7];
                    d2[r] = E[8]*c0  + E[9]*c1  + E[10]*c2 + E[11];
                    d3[r] = E[12]*c0 + E[13]*c1 + E[14]*c2 + E[15];
                }
                float ssr[4] = {0.f, 0.f, 0.f, 0.f};
                #pragma unroll
                for (int cti = 0; cti < CT; ++cti) {
                    int col = co + (colg * CT + cti) * 16 + la;
                    const float* iw = bias + col * 4;
                    const float* cw = bias2 + col * 4;
                    float cemb = E[3]*cw[0] + E[7]*cw[1] + E[11]*cw[2] + E[15]*cw[3];
                    #pragma unroll
                    for (int r = 0; r < 4; ++r) {
                        float e = d0[r]*iw[0] + d1[r]*iw[1] + d2[r]*iw[2] + d3[r]*iw[3] - cemb;
                        embv[cti][r] = e;
                        ssr[r] += e * e;
                    }
                }
                #pragma unroll
                for (int r = 0; r < 4; ++r) {
                    float s = ssr[r];
                    s += __shfl_xor(s, 1); s += __shfl_xor(s, 2);
                    s += __shfl_xor(s, 4); s += __shfl_xor(s, 8);
                    invr[r] = 1.0f / (sqrtf(s) + 1e-7f);
                }
            }
        }

        #pragma unroll
        for (int cti = 0; cti < CT; ++cti) {
            int ct = colg * CT + cti;
            int col = co + ct * 16 + la;
            float bv = 0.f;
            if constexpr (BIASF) bv = bc[col];
            if constexpr (STM == 1) {
                int row0 = rb + roww * 16 + g * 4;
                float vv[4];
                #pragma unroll
                for (int r = 0; r < 4; ++r) {
                    float v = acc[cti][r] + bv;
                    if constexpr (SCL)  v *= BN_S;
                    if constexpr (ACT)  v = gelu_f(v);
                    if constexpr (QSCL) v *= ATT_SCALE;
                    vv[r] = v;
                }
                float4 o4 = {vv[0], vv[1], vv[2], vv[3]};
                *(float4*)&((float*)ocv)[(size_t)col * PBEV + row0] = o4;
            } else {
                #pragma unroll
                for (int r = 0; r < 4; ++r) {
                    int row = rb + roww * 16 + g * 4 + r;
                    float v = acc[cti][r] + bv;
                    if constexpr (SCL)  v *= BN_S;
                    if constexpr (ACT)  v = gelu_f(v);
                    if constexpr (QSCL) v *= ATT_SCALE;
                    if constexpr (EMB) { if (set == 0) v += embv[cti][r] * invr[r]; }
                    if constexpr (ADDM == 1) { if (set == 0) v += addb[(size_t)row * 128 + col]; }
                    if constexpr (ADDM == 2) { if (set == 0) v += addb[(size_t)col * PBEV + row]; }
                    if constexpr (OUTBF) ((unsigned short*)ocv)[(size_t)row * NOT + col] = f2bf(v);
                    else                 ((float*)ocv)[(size_t)row * NOT + col] = v;
                }
            }
        }
    }
}

// ---------- merged k/v head GEMM (bf16 A, LN, dual weights, bf16 out) ----------
struct KVJob {
    const unsigned short* A;
    const unsigned short* W1;
    const float* b1;
    const unsigned short* W2;
    const float* b2;
    unsigned short* o1;
    unsigned short* o2;
};

__global__ __launch_bounds__(256)
void k_kvheads(KVJob jk, KVJob jv) {
    const KVJob j = (blockIdx.x < 288) ? jk : jv;
    const int rb = (blockIdx.x % 288) * 64;
    __shared__ unsigned short Al[64 * 136];
    __shared__ unsigned short Wl[128 * 136];
    const int t = threadIdx.x;
    const int lane = t & 63, wv = t >> 6;
    const int la = lane & 15, g = lane >> 4;

    {   // stage A rows (bf16 in) + LN
        int r = t >> 2, seg = t & 3;
        const unsigned short* ab = j.A + (size_t)(rb + r) * 128 + seg * 32;
        float v[32];
        #pragma unroll
        for (int j8 = 0; j8 < 4; ++j8) {
            u16x8 raw = *(const u16x8*)&ab[8 * j8];
            #pragma unroll
            for (int jj = 0; jj < 8; ++jj) v[8 * j8 + jj] = bf2f(raw[jj]);
        }
        float s = 0.f;
        #pragma unroll
        for (int jj = 0; jj < 32; ++jj) s += v[jj];
        s += __shfl_xor(s, 1); s += __shfl_xor(s, 2);
        float mu = s * (1.0f / 128.0f);
        float ss = 0.f;
        #pragma unroll
        for (int jj = 0; jj < 32; ++jj) { float d = v[jj] - mu; ss += d * d; }
        ss += __shfl_xor(ss, 1); ss += __shfl_xor(ss, 2);
        float rs = rsqrtf(ss * (1.0f / 128.0f) + LN_EPS);
        #pragma unroll
        for (int j8 = 0; j8 < 4; ++j8) {
            u16x8 o;
            #pragma unroll
            for (int jj = 0; jj < 8; ++jj) o[jj] = f2bf((v[8 * j8 + jj] - mu) * rs);
            *(u16x8*)&Al[r * 136 + seg * 32 + 8 * j8] = o;
        }
    }

    #pragma unroll 1
    for (int set = 0; set < 2; ++set) {
        const unsigned short* Wc = set ? j.W2 : j.W1;
        const float* bc = set ? j.b2 : j.b1;
        unsigned short* oc = set ? j.o2 : j.o1;
        if (set) __syncthreads();
        #pragma unroll
        for (int i = 0; i < 8; ++i) {
            int chunk = i * 256 + t;
            int c = chunk >> 4, k8 = chunk & 15;
            *(u16x8*)&Wl[c * 136 + k8 * 8] =
                *(const u16x8*)&Wc[(size_t)c * 128 + k8 * 8];
        }
        __syncthreads();
        short8 af[4];
        #pragma unroll
        for (int ks = 0; ks < 4; ++ks)
            af[ks] = *(short8*)&Al[(wv * 16 + la) * 136 + ks * 32 + g * 8];
        #pragma unroll
        for (int ct = 0; ct < 8; ++ct) {
            f32x4 acc = (f32x4){0.f, 0.f, 0.f, 0.f};
            #pragma unroll
            for (int ks = 0; ks < 4; ++ks) {
                short8 bf = *(short8*)&Wl[(ct * 16 + la) * 136 + ks * 32 + g * 8];
                acc = __builtin_amdgcn_mfma_f32_16x16x32_bf16(af[ks], bf, acc, 0, 0, 0);
            }
            int col = ct * 16 + la;
            float bv = bc[col];
            #pragma unroll
            for (int r = 0; r < 4; ++r) {
                int row = rb + wv * 16 + g * 4 + r;
                oc[(size_t)row * 128 + col] = f2bf(acc[r] + bv);
            }
        }
    }
}

// ---------- fused attn-out projection (+mean/+residual) + LN-MLP ----------
// AM=2: A=abuf (mean over 6 views, window permute); AM=0: A row-major.
template<int AM>
__global__ __launch_bounds__(256)
void k_projmlp(const float* __restrict__ Ain, const unsigned short* __restrict__ pwb,
               const float* __restrict__ pb, const float* __restrict__ resid,
               const unsigned short* __restrict__ w1b, const float* __restrict__ b1,
               const unsigned short* __restrict__ w2b, const float* __restrict__ b2,
               float* __restrict__ out) {
    __shared__ unsigned short Al[16 * 136];
    __shared__ unsigned short Wl[128 * 72];
    __shared__ unsigned short Gl[16 * 264];
    __shared__ float Xf[16 * 132];
    const int t = threadIdx.x;
    const int rb = blockIdx.x * 16;
    const int lane = t & 63, wv = t >> 6;
    const int la = lane & 15, g = lane >> 4;

    {   // stage A_in -> Al bf16
        int r = t >> 4, seg = t & 15;
        float v[8];
        if constexpr (AM == 2) {
            int hw = rb + r;
            int h = hw >> 6, w = hw & 63;
            int l = (h >> 3) * 8 + (w >> 3), ww = (h & 7) * 8 + (w & 7);
            const float* src = Ain + ((size_t)(l * 64 + ww)) * 6 * 128 + seg * 8;
            #pragma unroll
            for (int jj = 0; jj < 8; ++jj) v[jj] = 0.f;
            #pragma unroll
            for (int n = 0; n < 6; ++n) {
                float4 x0 = *(const float4*)&src[n * 128];
                float4 x1 = *(const float4*)&src[n * 128 + 4];
                v[0] += x0.x; v[1] += x0.y; v[2] += x0.z; v[3] += x0.w;
                v[4] += x1.x; v[5] += x1.y; v[6] += x1.z; v[7] += x1.w;
            }
            #pragma unroll
            for (int jj = 0; jj < 8; ++jj) v[jj] *= (1.0f / 6.0f);
        } else {
            const float* ar = Ain + (size_t)(rb + r) * 128 + seg * 8;
            *(float4*)&v[0] = *(const float4*)&ar[0];
            *(float4*)&v[4] = *(const float4*)&ar[4];
        }
        u16x8 o;
        #pragma unroll
        for (int jj = 0; jj < 8; ++jj) o[jj] = f2bf(v[jj]);
        *(u16x8*)&Al[r * 136 + seg * 8] = o;
    }
    __syncthreads();

    // proj: X = A . pw^T + pb + resid
    f32x4 acc2[2];
    acc2[0] = (f32x4){0.f, 0.f, 0.f, 0.f};
    acc2[1] = (f32x4){0.f, 0.f, 0.f, 0.f};
    #pragma unroll 1
    for (int kc = 0; kc < 2; ++kc) {
        if (kc) __syncthreads();
        {
            int c = t >> 1, s2 = t & 1;
            const unsigned short* wr = pwb + (size_t)c * 128 + kc * 64 + s2 * 32;
            #pragma unroll
            for (int j8 = 0; j8 < 4; ++j8)
                *(u16x8*)&Wl[c * 72 + s2 * 32 + 8 * j8] = *(const u16x8*)&wr[8 * j8];
        }
        __syncthreads();
        #pragma unroll
        for (int half = 0; half < 2; ++half) {
            short8 pf = *(short8*)&Al[la * 136 + kc * 64 + half * 32 + g * 8];
            #pragma unroll
            for (int ct = 0; ct < 2; ++ct) {
                short8 bf = *(short8*)&Wl[((wv * 2 + ct) * 16 + la) * 72 + half * 32 + g * 8];
                acc2[ct] = __builtin_amdgcn_mfma_f32_16x16x32_bf16(pf, bf, acc2[ct], 0, 0, 0);
            }
        }
    }
    __syncthreads();
    #pragma unroll
    for (int ct = 0; ct < 2; ++ct) {
        int col = (wv * 2 + ct) * 16 + la;
        float bv = pb[col];
        #pragma unroll
        for (int r = 0; r < 4; ++r) {
            int row = g * 4 + r;
            Xf[row * 132 + col] = acc2[ct][r] + bv
                                + resid[(size_t)(rb + row) * 128 + col];
        }
    }
    __syncthreads();

    {   // LN(X) -> Al
        int r = t >> 4, seg = t & 15;
        float v[8];
        #pragma unroll
        for (int jj = 0; jj < 8; ++jj) v[jj] = Xf[r * 132 + seg * 8 + jj];
        float s = 0.f;
        #pragma unroll
        for (int jj = 0; jj < 8; ++jj) s += v[jj];
        s += __shfl_xor(s, 1); s += __shfl_xor(s, 2);
        s += __shfl_xor(s, 4); s += __shfl_xor(s, 8);
        float mu = s * (1.0f / 128.0f);
        float ss = 0.f;
        #pragma unroll
        for (int jj = 0; jj < 8; ++jj) { float d = v[jj] - mu; ss += d * d; }
        ss += __shfl_xor(ss, 1); ss += __shfl_xor(ss, 2);
        ss += __shfl_xor(ss, 4); ss += __shfl_xor(ss, 8);
        float rs = rsqrtf(ss * (1.0f / 128.0f) + LN_EPS);
        u16x8 o;
        #pragma unroll
        for (int jj = 0; jj < 8; ++jj) o[jj] = f2bf((v[jj] - mu) * rs);
        *(u16x8*)&Al[r * 136 + seg * 8] = o;
    }
    __syncthreads();

    short8 af[4];
    #pragma unroll
    for (int ks = 0; ks < 4; ++ks)
        af[ks] = *(short8*)&Al[la * 136 + ks * 32 + g * 8];

    // MLP GEMM1 -> Gl
    #pragma unroll 1
    for (int cc = 0; cc < 4; ++cc) {
        {
            int c = t >> 2, s2 = t & 3;
            const unsigned short* wr = w1b + (size_t)(cc * 64 + c) * 128 + s2 * 32;
            #pragma unroll
            for (int j8 = 0; j8 < 4; ++j8)
                *(u16x8*)&Wl[c * 136 + s2 * 32 + 8 * j8] = *(const u16x8*)&wr[8 * j8];
        }
        __syncthreads();
        f32x4 acc = (f32x4){0.f, 0.f, 0.f, 0.f};
        #pragma unroll
        for (int ks = 0; ks < 4; ++ks) {
            short8 bf = *(short8*)&Wl[(wv * 16 + la) * 136 + ks * 32 + g * 8];
            acc = __builtin_amdgcn_mfma_f32_16x16x32_bf16(af[ks], bf, acc, 0, 0, 0);
        }
        int col = cc * 64 + wv * 16 + la;
        float bv = b1[col];
        #pragma unroll
        for (int r = 0; r < 4; ++r)
            Gl[(g * 4 + r) * 264 + col] = f2bf(gelu_f(acc[r] + bv));
        __syncthreads();
    }

    // MLP GEMM2
    acc2[0] = (f32x4){0.f, 0.f, 0.f, 0.f};
    acc2[1] = (f32x4){0.f, 0.f, 0.f, 0.f};
    #pragma unroll 1
    for (int kc = 0; kc < 4; ++kc) {
        {
            int c = t >> 1, s2 = t & 1;
            const unsigned short* wr = w2b + (size_t)c * 256 + kc * 64 + s2 * 32;
            #pragma unroll
            for (int j8 = 0; j8 < 4; ++j8)
                *(u16x8*)&Wl[c * 72 + s2 * 32 + 8 * j8] = *(const u16x8*)&wr[8 * j8];
        }
        __syncthreads();
        #pragma unroll
        for (int half = 0; half < 2; ++half) {
            short8 pf = *(short8*)&Gl[la * 264 + kc * 64 + half * 32 + g * 8];
            #pragma unroll
            for (int ct = 0; ct < 2; ++ct) {
                short8 bf = *(short8*)&Wl[((wv * 2 + ct) * 16 + la) * 72 + half * 32 + g * 8];
                acc2[ct] = __builtin_amdgcn_mfma_f32_16x16x32_bf16(pf, bf, acc2[ct], 0, 0, 0);
            }
        }
        __syncthreads();
    }
    #pragma unroll
    for (int ct = 0; ct < 2; ++ct) {
        int col = (wv * 2 + ct) * 16 + la;
        float bv = b2[col];
        #pragma unroll
        for (int r = 0; r < 4; ++r) {
            int row = g * 4 + r;
            out[(size_t)(rb + row) * 128 + col] = acc2[ct][r] + bv + Xf[row * 132 + col];
        }
    }
}

// ---------- fused mbproj(+SE,+zln) -> pm-FFN -> proj_out (gelu, transposed) ----------
__global__ __launch_bounds__(256)
void k_mbprojmlp(const float* __restrict__ dwo, const unsigned short* __restrict__ mbpwb,
                 const float* __restrict__ se, const float* __restrict__ zln,
                 const unsigned short* __restrict__ w1b, const float* __restrict__ b1,
                 const unsigned short* __restrict__ w2b, const float* __restrict__ b2,
                 const unsigned short* __restrict__ pob, const float* __restrict__ pb,
                 float* __restrict__ out) {
    __shared__ unsigned short Al[16 * 136];
    __shared__ unsigned short Wl[128 * 72];
    __shared__ unsigned short Gl[16 * 264];
    __shared__ float Xf[16 * 132];
    const int t = threadIdx.x;
    const int rb = blockIdx.x * 16;
    const int lane = t & 63, wv = t >> 6;
    const int la = lane & 15, g = lane >> 4;

    // mbproj: X = (dwo*se) . pw^T * BN_S + zln ; K=512 in 8 chunks
    f32x4 acc2[2];
    acc2[0] = (f32x4){0.f, 0.f, 0.f, 0.f};
    acc2[1] = (f32x4){0.f, 0.f, 0.f, 0.f};
    #pragma unroll 1
    for (int kc = 0; kc < 8; ++kc) {
        if (kc) __syncthreads();
        {
            int r = t >> 4, seg = t & 15;
            const float* ar = dwo + (size_t)(rb + r) * 512 + kc * 64 + seg * 4;
            float4 v = *(const float4*)ar;
            const float* sp = se + kc * 64 + seg * 4;
            v.x *= sp[0]; v.y *= sp[1]; v.z *= sp[2]; v.w *= sp[3];
            unsigned short* dst = &Al[r * 136 + seg * 4];
            dst[0] = f2bf(v.x); dst[1] = f2bf(v.y);
            dst[2] = f2bf(v.z); dst[3] = f2bf(v.w);
        }
        {
            int c = t >> 1, s2 = t & 1;
            const unsigned short* wr = mbpwb + (size_t)c * 512 + kc * 64 + s2 * 32;
            #pragma unroll
            for (int j8 = 0; j8 < 4; ++j8)
                *(u16x8*)&Wl[c * 72 + s2 * 32 + 8 * j8] = *(const u16x8*)&wr[8 * j8];
        }
        __syncthreads();
        #pragma unroll
        for (int half = 0; half < 2; ++half) {
            short8 pf = *(short8*)&Al[la * 136 + half * 32 + g * 8];
            #pragma unroll
            for (int ct = 0; ct < 2; ++ct) {
                short8 bf = *(short8*)&Wl[((wv * 2 + ct) * 16 + la) * 72 + half * 32 + g * 8];
                acc2[ct] = __builtin_amdgcn_mfma_f32_16x16x32_bf16(pf, bf, acc2[ct], 0, 0, 0);
            }
        }
    }
    __syncthreads();
    #pragma unroll
    for (int ct = 0; ct < 2; ++ct) {
        int col = (wv * 2 + ct) * 16 + la;
        #pragma unroll
        for (int r = 0; r < 4; ++r) {
            int row = g * 4 + r;
            Xf[row * 132 + col] = acc2[ct][r] * BN_S
                                + zln[(size_t)(rb + row) * 128 + col];
        }
    }
    __syncthreads();

    {   // Al = bf16(X)  (pm FFN has no LN)
        int r = t >> 4, seg = t & 15;
        u16x8 o;
        #pragma unroll
        for (int jj = 0; jj < 8; ++jj) o[jj] = f2bf(Xf[r * 132 + seg * 8 + jj]);
        *(u16x8*)&Al[r * 136 + seg * 8] = o;
    }
    __syncthreads();

    short8 af[4];
    #pragma unroll
    for (int ks = 0; ks < 4; ++ks)
        af[ks] = *(short8*)&Al[la * 136 + ks * 32 + g * 8];

    // FFN GEMM1 -> Gl
    #pragma unroll 1
    for (int cc = 0; cc < 4; ++cc) {
        {
            int c = t >> 2, s2 = t & 3;
            const unsigned short* wr = w1b + (size_t)(cc * 64 + c) * 128 + s2 * 32;
            #pragma unroll
            for (int j8 = 0; j8 < 4; ++j8)
                *(u16x8*)&Wl[c * 136 + s2 * 32 + 8 * j8] = *(const u16x8*)&wr[8 * j8];
        }
        __syncthreads();
        f32x4 acc = (f32x4){0.f, 0.f, 0.f, 0.f};
        #pragma unroll
        for (int ks = 0; ks < 4; ++ks) {
            short8 bf = *(short8*)&Wl[(wv * 16 + la) * 136 + ks * 32 + g * 8];
            acc = __builtin_amdgcn_mfma_f32_16x16x32_bf16(af[ks], bf, acc, 0, 0, 0);
        }
        int col = cc * 64 + wv * 16 + la;
        float bv = b1[col];
        #pragma unroll
        for (int r = 0; r < 4; ++r)
            Gl[(g * 4 + r) * 264 + col] = f2bf(gelu_f(acc[r] + bv));
        __syncthreads();
    }

    // FFN GEMM2 -> Y ; write Y bf16 to Al
    acc2[0] = (f32x4){0.f, 0.f, 0.f, 0.f};
    acc2[1] = (f32x4){0.f, 0.f, 0.f, 0.f};
    #pragma unroll 1
    for (int kc = 0; kc < 4; ++kc) {
        {
            int c = t >> 1, s2 = t & 1;
            const unsigned short* wr = w2b + (size_t)c * 256 + kc * 64 + s2 * 32;
            #pragma unroll
            for (int j8 = 0; j8 < 4; ++j8)
                *(u16x8*)&Wl[c * 72 + s2 * 32 + 8 * j8] = *(const u16x8*)&wr[8 * j8];
        }
        __syncthreads();
        #pragma unroll
        for (int half = 0; half < 2; ++half) {
            short8 pf = *(short8*)&Gl[la * 264 + kc * 64 + half * 32 + g * 8];
            #pragma unroll
            for (int ct = 0; ct < 2; ++ct) {
                short8 bf = *(short8*)&Wl[((wv * 2 + ct) * 16 + la) * 72 + half * 32 + g * 8];
                acc2[ct] = __builtin_amdgcn_mfma_f32_16x16x32_bf16(pf, bf, acc2[ct], 0, 0, 0);
            }
        }
        __syncthreads();
    }
    #pragma unroll
    for (int ct = 0; ct < 2; ++ct) {
        int col = (wv * 2 + ct) * 16 + la;
        float bv = b2[col];
        #pragma unroll
        for (int r = 0; r < 4; ++r) {
            int row = g * 4 + r;
            float y = acc2[ct][r] + bv + Xf[row * 132 + col];
            Al[row * 136 + col] = f2bf(y);
        }
    }
    __syncthreads();

    // proj_out: Z = gelu(Y . po^T + pb), transposed store
    f32x4 acc3[2];
    acc3[0] = (f32x4){0.f, 0.f, 0.f, 0.f};
    acc3[1] = (f32x4){0.f, 0.f, 0.f, 0.f};
    #pragma unroll 1
    for (int kc = 0; kc < 2; ++kc) {
        if (kc) __syncthreads();
        {
            int c = t >> 1, s2 = t & 1;
            const unsigned short* wr = pob + (size_t)c * 128 + kc * 64 + s2 * 32;
            #pragma unroll
            for (int j8 = 0; j8 < 4; ++j8)
                *(u16x8*)&Wl[c * 72 + s2 * 32 + 8 * j8] = *(const u16x8*)&wr[8 * j8];
        }
        __syncthreads();
        #pragma unroll
        for (int half = 0; half < 2; ++half) {
            short8 pf = *(short8*)&Al[la * 136 + kc * 64 + half * 32 + g * 8];
            #pragma unroll
            for (int ct = 0; ct < 2; ++ct) {
                short8 bf = *(short8*)&Wl[((wv * 2 + ct) * 16 + la) * 72 + half * 32 + g * 8];
                acc3[ct] = __builtin_amdgcn_mfma_f32_16x16x32_bf16(pf, bf, acc3[ct], 0, 0, 0);
            }
        }
    }
    #pragma unroll
    for (int ct = 0; ct < 2; ++ct) {
        int col = (wv * 2 + ct) * 16 + la;
        float bv = pb[col];
        float4 o4;
        o4.x = gelu_f(acc3[ct][0] + bv);
        o4.y = gelu_f(acc3[ct][1] + bv);
        o4.z = gelu_f(acc3[ct][2] + bv);
        o4.w = gelu_f(acc3[ct][3] + bv);
        *(float4*)&out[(size_t)col * PBEV + rb + g * 4] = o4;
    }
}

// ---------- MFMA flash attention (S^T trick, shfl P re-layout) ----------
template<int MODE>
__global__ __launch_bounds__(MODE == 1 ? 512 : 256)
void k_attn_mfma(const unsigned short* __restrict__ qh, const unsigned short* __restrict__ kh,
                 const unsigned short* __restrict__ vh, float* __restrict__ aout) {
    constexpr int WAVES = (MODE == 1) ? 8 : 4;
    constexpr int QTPW  = (MODE == 1) ? 3 : 1;
    constexpr int T = WAVES * 64;
    const int l = blockIdx.x, m = blockIdx.y;
    const int xw = l >> 3, yw = l & 7;
    const int t = threadIdx.x;
    const int lane = t & 63, wv = t >> 6;
    const int la = lane & 15, g = lane >> 4;

    __shared__ unsigned short Kl[KROWS * 40];
    __shared__ unsigned short Vt[32 * 312];

    for (int i = t; i < KROWS * 4; i += T) {
        int row = i >> 2, seg = i & 3;
        int n = row / 48, kk = row % 48;
        int k1 = kk / 12, k2 = kk % 12;
        int h, w;
        if (MODE == 1) { h = xw * 4 + k1;  w = yw * 12 + k2; }
        else           { h = k1 * 8 + xw;  w = k2 * 8 + yw;  }
        size_t src = ((size_t)(n * PIMG + h * FWW + w)) * 128 + m * DHD + seg * 8;
        short8 kv = *(const short8*)&kh[src];
        *(short8*)&Kl[row * 40 + seg * 8] = kv;
        short8 vv = *(const short8*)&vh[src];
        #pragma unroll
        for (int j = 0; j < 8; ++j)
            Vt[(seg * 8 + j) * 312 + row] = (unsigned short)vv[j];
    }

    short8 qf[QTPW];
    #pragma unroll
    for (int qt = 0; qt < QTPW; ++qt) {
        int q = (wv * QTPW + qt) * 16 + la;
        int row;
        if (MODE == 1) {
            int n = q >> 6, ww = q & 63;
            row = n * PBEV + (xw * 8 + (ww >> 3)) * 64 + yw * 8 + (ww & 7);
        } else {
            row = ((q >> 3) * 8 + xw) * 64 + (q & 7) * 8 + yw;
        }
        qf[qt] = *(const short8*)&qh[(size_t)row * 128 + m * DHD + g * 8];
    }
    __syncthreads();

    f32x4 acc[QTPW][2];
    float srow[QTPW];
    #pragma unroll
    for (int qt = 0; qt < QTPW; ++qt) {
        acc[qt][0] = (f32x4){0.f, 0.f, 0.f, 0.f};
        acc[qt][1] = (f32x4){0.f, 0.f, 0.f, 0.f};
        srow[qt] = 0.f;
    }
    const int a0 = la + 32 * (g & 1);
    const int a1 = a0 + 16;
    const bool selA = (g < 2);

    #pragma unroll 1
    for (int c = 0; c < 9; ++c) {
        const int kk0 = c * 32;
        short8 kf0 = *(short8*)&Kl[(kk0 + la) * 40 + g * 8];
        short8 kf1 = *(short8*)&Kl[(kk0 + 16 + la) * 40 + g * 8];
        short8 vf0 = *(short8*)&Vt[la * 312 + kk0 + g * 8];
        short8 vf1 = *(short8*)&Vt[(16 + la) * 312 + kk0 + g * 8];
        #pragma unroll
        for (int qt = 0; qt < QTPW; ++qt) {
            f32x4 sA = __builtin_amdgcn_mfma_f32_16x16x32_bf16(kf0, qf[qt], (f32x4){0.f,0.f,0.f,0.f}, 0, 0, 0);
            f32x4 sB = __builtin_amdgcn_mfma_f32_16x16x32_bf16(kf1, qf[qt], (f32x4){0.f,0.f,0.f,0.f}, 0, 0, 0);
            float pA[4], pB[4];
            #pragma unroll
            for (int r = 0; r < 4; ++r) { pA[r] = __expf(sA[r]); pB[r] = __expf(sB[r]); }
            srow[qt] += ((pA[0] + pA[1]) + (pA[2] + pA[3]))
                      + ((pB[0] + pB[1]) + (pB[2] + pB[3]));
            unsigned int loA = (unsigned int)f2bf(pA[0]) | ((unsigned int)f2bf(pA[1]) << 16);
            unsigned int hiA = (unsigned int)f2bf(pA[2]) | ((unsigned int)f2bf(pA[3]) << 16);
            unsigned int loB = (unsigned int)f2bf(pB[0]) | ((unsigned int)f2bf(pB[1]) << 16);
            unsigned int hiB = (unsigned int)f2bf(pB[2]) | ((unsigned int)f2bf(pB[3]) << 16);
            int w0A = __shfl((int)loA, a0); int w0B = __shfl((int)loB, a0);
            int w1A = __shfl((int)hiA, a0); int w1B = __shfl((int)hiB, a0);
            int w2A = __shfl((int)loA, a1); int w2B = __shfl((int)loB, a1);
            int w3A = __shfl((int)hiA, a1); int w3B = __shfl((int)hiB, a1);
            union { int u[4]; short8 s; } pu;
            pu.u[0] = selA ? w0A : w0B;
            pu.u[1] = selA ? w1A : w1B;
            pu.u[2] = selA ? w2A : w2B;
            pu.u[3] = selA ? w3A : w3B;
            acc[qt][0] = __builtin_amdgcn_mfma_f32_16x16x32_bf16(pu.s, vf0, acc[qt][0], 0, 0, 0);
            acc[qt][1] = __builtin_amdgcn_mfma_f32_16x16x32_bf16(pu.s, vf1, acc[qt][1], 0, 0, 0);
        }
    }

    #pragma unroll
    for (int qt = 0; qt < QTPW; ++qt) {
        float s = srow[qt];
        s += __shfl_xor(s, 16);
        s += __shfl_xor(s, 32);
        #pragma unroll
        for (int r = 0; r < 4; ++r) {
            float sq = __shfl(s, g * 4 + r);
            float inv = 1.0f / sq;
            int q = (wv * QTPW + qt) * 16 + g * 4 + r;
            size_t orow;
            if (MODE == 1) {
                int n = q >> 6, ww = q & 63;
                orow = (size_t)(l * 64 + ww) * 6 + n;
            } else {
                orow = (size_t)(((q >> 3) * 8 + xw) * 64 + (q & 7) * 8 + yw);
            }
            float* ap = aout + orow * 128 + m * DHD;
            ap[la]      = acc[qt][0][r] * inv;
            ap[16 + la] = acc[qt][1][r] * inv;
        }
    }
}

// ---------- depthwise 3x3 + gelu + SE partials ----------
__global__ void k_dwconv(const float* __restrict__ ex, const float* __restrict__ dwgt,
                         float* __restrict__ dwout, float* __restrict__ separt) {
    const int TILE = 16;
    int ch = threadIdx.x;
    int hw0 = blockIdx.x * TILE;
    float wreg[9];
    #pragma unroll
    for (int i = 0; i < 9; ++i) wreg[i] = dwgt[ch * 9 + i];
    float sacc = 0.f;
    for (int ti = 0; ti < TILE; ++ti) {
        int hw = hw0 + ti;
        int h = hw >> 6, w = hw & 63;
        float s = 0.f;
        #pragma unroll
        for (int dy = -1; dy <= 1; ++dy) {
            int h2 = h + dy;
            if (h2 < 0 || h2 >= 64) continue;
            #pragma unroll
            for (int dx = -1; dx <= 1; ++dx) {
                int w2 = w + dx;
                if (w2 < 0 || w2 >= 64) continue;
                s += ex[((size_t)(h2 * 64 + w2)) * 512 + ch] * wreg[(dy + 1) * 3 + (dx + 1)];
            }
        }
        float o = gelu_f(s * BN_S);
        dwout[(size_t)hw * 512 + ch] = o;
        sacc += o;
    }
    separt[(size_t)blockIdx.x * 512 + ch] = sacc;
}

// ---------- SE reduce stage 1 ----------
__global__ void k_sered(const float* __restrict__ separt, float* __restrict__ separt2) {
    int t = threadIdx.x, bb = blockIdx.x;
    float s = 0.f;
    #pragma unroll
    for (int i = 0; i < 16; ++i)
        s += separt[(size_t)(bb * 16 + i) * 512 + t];
    separt2[(size_t)bb * 512 + t] = s;
}

// ---------- SE final ----------
__global__ void k_se(const float* __restrict__ separt2,
                     const float* __restrict__ s1w, const float* __restrict__ s1b,
                     const float* __restrict__ s2w, const float* __restrict__ s2b,
                     float* __restrict__ se) {
    __shared__ float mean[512];
    __shared__ float s1[32];
    int t = threadIdx.x;
    float s = 0.f;
    #pragma unroll
    for (int b = 0; b < 16; ++b) s += separt2[b * 512 + t];
    mean[t] = s * (1.0f / 4096.0f);
    __syncthreads();
    int u = t >> 4, seg = t & 15;
    float acc = 0.f;
    #pragma unroll
    for (int j = 0; j < 32; ++j) {
        int c = seg + 16 * j;
        acc += mean[c] * s1w[u * 512 + c];
    }
    acc += __shfl_xor(acc, 1); acc += __shfl_xor(acc, 2);
    acc += __shfl_xor(acc, 4); acc += __shfl_xor(acc, 8);
    if (seg == 0) s1[u] = gelu_f(acc + s1b[u]);
    __syncthreads();
    float a2 = s2b[t];
    #pragma unroll
    for (int j = 0; j < 32; ++j) a2 += s1[j] * s2w[t * 32 + j];
    se[t] = 1.0f / (1.0f + __expf(-a2));
}

extern "C" void kernel_launch(void* const* d_in, const int* in_sizes, int n_in,
                              void* d_out, int out_size, void* d_ws, size_t ws_size,
                              hipStream_t stream) {
    (void)in_sizes; (void)n_in; (void)out_size; (void)ws_size;
    const float* x      = (const float*)d_in[1];
    const float* feat   = (const float*)d_in[2];
    const float* I_inv  = (const float*)d_in[3];
    const float* E_inv  = (const float*)d_in[4];
    const float* bev    = (const float*)d_in[5];
    const float* fl_w   = (const float*)d_in[6];
    const float* fp_w   = (const float*)d_in[7];
    const float* be_w   = (const float*)d_in[8];
    const float* be_b   = (const float*)d_in[9];
    const float* ie_w   = (const float*)d_in[10];
    const float* ce_w   = (const float*)d_in[11];
    const float* a1_qw  = (const float*)d_in[12];
    const float* a1_qb  = (const float*)d_in[13];
    const float* a1_kw  = (const float*)d_in[14];
    const float* a1_kb  = (const float*)d_in[15];
    const float* a1_vw  = (const float*)d_in[16];
    const float* a1_vb  = (const float*)d_in[17];
    const float* a1_pw  = (const float*)d_in[18];
    const float* a1_pb  = (const float*)d_in[19];
    const float* a2_qw  = (const float*)d_in[20];
    const float* a2_qb  = (const float*)d_in[21];
    const float* a2_kw  = (const float*)d_in[22];
    const float* a2_kb  = (const float*)d_in[23];
    const float* a2_vw  = (const float*)d_in[24];
    const float* a2_vb  = (const float*)d_in[25];
    const float* a2_pw  = (const float*)d_in[26];
    const float* a2_pb  = (const float*)d_in[27];
    const float* m1_w1  = (const float*)d_in[28];
    const float* m1_b1  = (const float*)d_in[29];
    const float* m1_w2  = (const float*)d_in[30];
    const float* m1_b2  = (const float*)d_in[31];
    const float* m2_w1  = (const float*)d_in[32];
    const float* m2_b1  = (const float*)d_in[33];
    const float* m2_w2  = (const float*)d_in[34];
    const float* m2_b2  = (const float*)d_in[35];
    const float* mb_ew  = (const float*)d_in[36];
    const float* mb_dw  = (const float*)d_in[37];
    const float* mb_s1w = (const float*)d_in[38];
    const float* mb_s1b = (const float*)d_in[39];
    const float* mb_s2w = (const float*)d_in[40];
    const float* mb_s2b = (const float*)d_in[41];
    const float* mb_pw  = (const float*)d_in[42];
    const float* pm_w1  = (const float*)d_in[43];
    const float* pm_b1  = (const float*)d_in[44];
    const float* pm_w2  = (const float*)d_in[45];
    const float* pm_b2  = (const float*)d_in[46];
    const float* po_w   = (const float*)d_in[47];
    const float* po_b   = (const float*)d_in[48];

    float* ws = (float*)d_ws;
    float* x_cl   = ws + 0;          // 524288
    unsigned short* key_b = (unsigned short*)(ws + 524288);
    unsigned short* val_b = (unsigned short*)(ws + 1703936);
    unsigned short* qh1b  = (unsigned short*)(ws + 2883584);
    unsigned short* kh1b  = (unsigned short*)(ws + 4456448);
    unsigned short* vh1b  = (unsigned short*)(ws + 5636096);
    unsigned short* kh2b  = (unsigned short*)(ws + 6815744);
    unsigned short* vh2b  = (unsigned short*)(ws + 7995392);
    float* abuf   = ws + 9175040;    // 3145728
    float* qimg   = ws + 12320768;
    float* qimg2  = ws + 12845056;
    float* zln    = ws + 13369344;
    float* abuf2  = ws + 13893632;
    float* expandb = ws + 14942208;  // 2097152
    float* dwout   = ws + 17039360;  // 2097152
    float* separt  = ws + 19136512;  // 131072
    float* separt2 = ws + 19267584;  // 8192
    float* sebuf   = ws + 19275776;  // 512
    unsigned short* wb = (unsigned short*)(ws + 19276288);  // 507904 u16
    unsigned short* qh2b = qh1b;

    // weight conversion + x transpose
    k_cvtw<<<248, 256, 0, stream>>>(fp_w, fl_w, a1_qw, a1_kw, a2_kw, a1_vw, a2_vw,
                                    a1_pw, m1_w1, m1_w2, a2_qw, a2_pw, m2_w1, m2_w2,
                                    mb_ew, mb_pw, pm_w1, pm_w2, po_w, wb);
    k_transx<<<dim3(128, 4), 256, 0, stream>>>(x, x_cl);

    // key/val (feature transpose + img-embed fused), bf16 out
    k_gemm_mfma<64,1,128, 1,0,0,0,0, 0,0,0,1, 1,0,0,1,1><<<288, 256, 0, stream>>>(
        feat, (const float*)(wb + OFF_FP), ie_w, E_inv, I_inv,
        (const float*)(wb + OFF_FL), ce_w, val_b, nullptr, key_b);

    // q head (query gen fused, pre-scaled); k/v heads merged dual
    k_gemm_mfma<64,1,128, 3,1,1,0,0, 0,0,0,0, 1,1,0,0,1><<<384, 256, 0, stream>>>(
        nullptr, (const float*)(wb + OFF_A1QW), a1_qb, bev, x_cl, be_w, be_b,
        (void*)E_inv, (float*)ce_w, qh1b);
    {
        KVJob jk = { key_b, wb + OFF_A1KW, a1_kb, wb + OFF_A2KW, a2_kb, kh1b, kh2b };
        KVJob jv = { val_b, wb + OFF_A1VW, a1_vb, wb + OFF_A2VW, a2_vb, vh1b, vh2b };
        k_kvheads<<<576, 256, 0, stream>>>(jk, jv);
    }
    k_attn_mfma<1><<<dim3(64, HEADS), 512, 0, stream>>>(qh1b, kh1b, vh1b, abuf);
    k_projmlp<2><<<256, 256, 0, stream>>>(abuf, wb + OFF_A1PW, a1_pb, x_cl,
                                          wb + OFF_M1W1, m1_b1, wb + OFF_M1W2, m1_b2, qimg);

    // stage 2
    k_gemm_mfma<16,1,128, 0,1,1,0,0, 0,0,0,0, 1,1,0,0,1><<<256, 256, 0, stream>>>(
        qimg, (const float*)(wb + OFF_A2QW), a2_qb, nullptr, nullptr, nullptr,
        nullptr, nullptr, nullptr, qh2b);
    k_attn_mfma<2><<<dim3(64, HEADS), 256, 0, stream>>>(qh2b, kh2b, vh2b, abuf2);
    k_projmlp<0><<<256, 256, 0, stream>>>(abuf2, wb + OFF_A2PW, a2_pb, qimg,
                                          wb + OFF_M2W1, m2_b1, wb + OFF_M2W2, m2_b2, qimg2);

    // stage 3
    k_gemm_mfma<16,1,512, 0,1,0,1,1, 0,0,0,0, 0,0,1,0,1><<<dim3(256, 4), 256, 0, stream>>>(
        qimg2, (const float*)(wb + OFF_MBEW), nullptr, nullptr, nullptr, nullptr,
        nullptr, nullptr, zln, expandb);
    k_dwconv<<<256, 512, 0, stream>>>(expandb, mb_dw, dwout, separt);
    k_sered<<<16, 512, 0, stream>>>(separt, separt2);
    k_se<<<1, 512, 0, stream>>>(separt2, mb_s1w, mb_s1b, mb_s2w, mb_s2b, sebuf);
    k_mbprojmlp<<<256, 256, 0, stream>>>(dwout, wb + OFF_MBPW, sebuf, zln,
                                         wb + OFF_PMW1, pm_b1, wb + OFF_PMW2, pm_b2,
                                         wb + OFF_POW, po_b, (float*)d_out);
}